// Round 10
// baseline (1893.508 us; speedup 1.0000x reference)
//
#include <hip/hip_runtime.h>
#include <hip/hip_cooperative_groups.h>
#include <math.h>

namespace cg = cooperative_groups;

#define HID 256
#define XS_STRIDE 36
#define X2_STRIDE 260
#define SMEM_FLOATS 9344   // gemm union: xsT[256*36] vs x2s[32*260]+sred[4*256]

struct GP {
    const float* nf; const int* ei; const int* eid; const int* epos;
    const float* id_emb; const float* pos_emb;
    const float* ew_w1; const float* ew_b1; const float* ew_w2; const float* ew_b2;
    const float* c1w; const float* c1b; const float* c2w; const float* c2b;
    const float* aw1; const float* ab1; const float* aw2; const float* ab2;
    const float* cw1; const float* cb1; const float* cw2; const float* cb2;
    const float* cw3; const float* cb3;
    float* deg; int* cnt; float* gsum;
    float* A; float* P; float* ew; int2* csr;
    int* row_ptr; int* cursor; int* bsums; int* bscan;
    float4* nf4; float4* T3; float* gbias;
    float* out;
    int N, E, NB;
    float invN;
};

// ---------- stage: zero deg|cnt|gsum (contiguous)
__device__ __forceinline__ void dev_init(const GP& p) {
    int tot = 2 * p.N + HID;
    for (int i = blockIdx.x * blockDim.x + threadIdx.x; i < tot; i += gridDim.x * blockDim.x)
        ((float*)p.deg)[i] = 0.f;   // deg,cnt,gsum contiguous
}

// ---------- stage: edge MLP + degree/count atomics
__device__ __forceinline__ void dev_edge(const GP& p, float* smem) {
    int t = threadIdx.x;
    if (t < 100) smem[t] = p.ew_w1[t];
    if (t < 10) { smem[100 + t] = p.ew_b1[t]; smem[110 + t] = p.ew_w2[t]; }
    if (t == 0) smem[120] = p.ew_b2[0];
    __syncthreads();
    for (int e = blockIdx.x * blockDim.x + t; e < p.E; e += gridDim.x * blockDim.x) {
        int id = p.eid[e];
        int pp = p.epos[e];
        const float4* ide = (const float4*)(p.id_emb + (size_t)id * 8);
        float4 fa = ide[0], fb = ide[1];
        float f[10];
        f[0] = fa.x; f[1] = fa.y; f[2] = fa.z; f[3] = fa.w;
        f[4] = fb.x; f[5] = fb.y; f[6] = fb.z; f[7] = fb.w;
        f[8] = p.pos_emb[pp * 2 + 0];
        f[9] = p.pos_emb[pp * 2 + 1];
        float acc = smem[120];
#pragma unroll
        for (int j = 0; j < 10; j++) {
            float h = smem[100 + j];
#pragma unroll
            for (int i = 0; i < 10; i++) h += f[i] * smem[i * 10 + j];
            h = fmaxf(h, 0.f);
            acc += h * smem[110 + j];
        }
        float w = 1.f / (1.f + expf(-acc));
        p.ew[e] = w;
        int dst = p.ei[p.E + e];
        atomicAdd(&p.deg[dst], w);
        atomicAdd(&p.cnt[dst], 1);
    }
}

// ---------- stage: dinv + pack nf
__device__ __forceinline__ void dev_dinv(const GP& p) {
    for (int i = blockIdx.x * blockDim.x + threadIdx.x; i < p.N; i += gridDim.x * blockDim.x) {
        p.deg[i] = 1.f / sqrtf(p.deg[i] + 1.f);
        p.nf4[i] = make_float4(p.nf[i * 3 + 0], p.nf[i * 3 + 1], p.nf[i * 3 + 2], 0.f);
    }
}

// ---------- scan phase a: per-block (256-chunk) exclusive scan, coalesced
__device__ __forceinline__ void dev_scan_a(const GP& p, float* smemf) {
    int b = blockIdx.x, t = threadIdx.x;
    if (b >= p.NB) return;
    int* s = (int*)smemf;
    int i = b * 256 + t;
    int v = (i < p.N) ? p.cnt[i] : 0;
    s[t] = v;
    __syncthreads();
    for (int off = 1; off < 256; off <<= 1) {
        int u = (t >= off) ? s[t - off] : 0;
        __syncthreads();
        s[t] += u;
        __syncthreads();
    }
    int incl = s[t];
    if (i < p.N) p.row_ptr[i] = incl - v;   // local exclusive
    if (t == 255) p.bsums[b] = incl;        // block total
}

// ---------- scan phase b: block 0 scans block sums (NB<=256)
__device__ __forceinline__ void dev_scan_b(const GP& p, float* smemf) {
    if (blockIdx.x != 0) return;
    int t = threadIdx.x;
    int* s = (int*)smemf;
    int v = (t < p.NB) ? p.bsums[t] : 0;
    s[t] = v;
    __syncthreads();
    for (int off = 1; off < 256; off <<= 1) {
        int u = (t >= off) ? s[t - off] : 0;
        __syncthreads();
        s[t] += u;
        __syncthreads();
    }
    if (t < p.NB) p.bscan[t] = s[t] - v;
    if (t == 255) p.row_ptr[p.N] = s[255];  // grand total
}

// ---------- scan phase c: add block offsets, copy to cursor
__device__ __forceinline__ void dev_scan_c(const GP& p) {
    int b = blockIdx.x, t = threadIdx.x;
    if (b >= p.NB) return;
    int i = b * 256 + t;
    if (i < p.N) {
        int rp = p.row_ptr[i] + p.bscan[b];
        p.row_ptr[i] = rp;
        p.cursor[i] = rp;
    }
}

// ---------- stage: fill CSR
__device__ __forceinline__ void dev_fill(const GP& p) {
    for (int e = blockIdx.x * blockDim.x + threadIdx.x; e < p.E; e += gridDim.x * blockDim.x) {
        int src = p.ei[e];
        int dst = p.ei[p.E + e];
        int slot = atomicAdd(&p.cursor[dst], 1);
        float norm = p.deg[src] * p.ew[e] * p.deg[dst];
        p.csr[slot] = make_int2(src, __float_as_int(norm));
    }
}

// ---------- stage: layer-1 aggregation on raw packed features
__device__ __forceinline__ void dev_agg3(const GP& p) {
    for (int n = blockIdx.x * blockDim.x + threadIdx.x; n < p.N; n += gridDim.x * blockDim.x) {
        int s = p.row_ptr[n];
        int e = p.row_ptr[n + 1];
        float ax = 0.f, ay = 0.f, az = 0.f;
        for (int i = s; i < e; i++) {
            int2 sn = p.csr[i];
            float w = __int_as_float(sn.y);
            float4 v = p.nf4[sn.x];
            ax = fmaf(w, v.x, ax);
            ay = fmaf(w, v.y, ay);
            az = fmaf(w, v.z, az);
        }
        float d = p.deg[n];
        float dd = d * d;
        float4 v = p.nf4[n];
        ax = fmaf(dd, v.x, ax);
        ay = fmaf(dd, v.y, ay);
        az = fmaf(dd, v.z, az);
        p.T3[n] = make_float4(ax, ay, az, 0.f);
    }
}

// ---------- stage: layer-2 aggregation with x1 recomputed on the fly
__device__ __forceinline__ void dev_gather(const GP& p) {
    int lane = threadIdx.x & 63;
    int wv = threadIdx.x >> 6;
    const float4 w0 = *(const float4*)(p.c1w + 4 * lane);
    const float4 w1 = *(const float4*)(p.c1w + HID + 4 * lane);
    const float4 w2 = *(const float4*)(p.c1w + 2 * HID + 4 * lane);
    const float4 bv = *(const float4*)(p.c1b + 4 * lane);
    int ngrp = (p.N + 3) / 4;
    for (int grp = blockIdx.x; grp < ngrp; grp += gridDim.x) {
        int n = grp * 4 + wv;
        if (n >= p.N) continue;
        int s = p.row_ptr[n];
        int e = p.row_ptr[n + 1];
        float4 acc = make_float4(0.f, 0.f, 0.f, 0.f);
        for (int i = s; i < e; i++) {
            int2 sn = p.csr[i];
            float w = __int_as_float(sn.y);
            float4 t = p.T3[sn.x];
            float xx = fmaxf(fmaf(t.x, w0.x, fmaf(t.y, w1.x, fmaf(t.z, w2.x, bv.x))), 0.f);
            float xy = fmaxf(fmaf(t.x, w0.y, fmaf(t.y, w1.y, fmaf(t.z, w2.y, bv.y))), 0.f);
            float xz = fmaxf(fmaf(t.x, w0.z, fmaf(t.y, w1.z, fmaf(t.z, w2.z, bv.z))), 0.f);
            float xw = fmaxf(fmaf(t.x, w0.w, fmaf(t.y, w1.w, fmaf(t.z, w2.w, bv.w))), 0.f);
            acc.x = fmaf(w, xx, acc.x);
            acc.y = fmaf(w, xy, acc.y);
            acc.z = fmaf(w, xz, acc.z);
            acc.w = fmaf(w, xw, acc.w);
        }
        float d = p.deg[n];
        float dd = d * d;
        float4 t = p.T3[n];
        float xx = fmaxf(fmaf(t.x, w0.x, fmaf(t.y, w1.x, fmaf(t.z, w2.x, bv.x))), 0.f);
        float xy = fmaxf(fmaf(t.x, w0.y, fmaf(t.y, w1.y, fmaf(t.z, w2.y, bv.y))), 0.f);
        float xz = fmaxf(fmaf(t.x, w0.z, fmaf(t.y, w1.z, fmaf(t.z, w2.z, bv.z))), 0.f);
        float xw = fmaxf(fmaf(t.x, w0.w, fmaf(t.y, w1.w, fmaf(t.z, w2.w, bv.w))), 0.f);
        acc.x = fmaf(dd, xx, acc.x);
        acc.y = fmaf(dd, xy, acc.y);
        acc.z = fmaf(dd, xz, acc.z);
        acc.w = fmaf(dd, xw, acc.w);
        *(float4*)(p.A + (size_t)n * HID + lane * 4) = acc;
    }
}

// ---------- stage: fused double GEMM (proven R7 body), grid-stride over 32-row tiles
__device__ __forceinline__ void dev_gemm(const GP& p, float* smem) {
    int tid = threadIdx.x;
    int ntiles = (p.N + 31) / 32;
    for (int tile = blockIdx.x; tile < ntiles; tile += gridDim.x) {
        int n0 = tile * 32;
        // stage A tile transposed
        {
            int r = tid >> 3;
            int c8 = tid & 7;
            int n = n0 + r;
#pragma unroll
            for (int j = 0; j < 8; j++) {
                int c4 = c8 + 8 * j;
                float4 v = make_float4(0.f, 0.f, 0.f, 0.f);
                if (n < p.N) v = *(const float4*)(p.A + (size_t)n * HID + 4 * c4);
                int col = 4 * c4;
                smem[(col + 0) * XS_STRIDE + r] = v.x;
                smem[(col + 1) * XS_STRIDE + r] = v.y;
                smem[(col + 2) * XS_STRIDE + r] = v.z;
                smem[(col + 3) * XS_STRIDE + r] = v.w;
            }
        }
        __syncthreads();
        int tx = tid & 63;
        int ty = tid >> 6;
        // phase 1
        float4 acc[8];
#pragma unroll
        for (int i = 0; i < 8; i++) acc[i] = make_float4(0.f, 0.f, 0.f, 0.f);
        {
            const float* Wc = p.c2w + 4 * tx;
            const float* xbase = &smem[ty * 8];
            for (int k0 = 0; k0 < HID; k0 += 8) {
                float4 w[8];
#pragma unroll
                for (int j = 0; j < 8; j++) w[j] = *(const float4*)(Wc + (size_t)(k0 + j) * HID);
#pragma unroll
                for (int j = 0; j < 8; j++) {
                    const float* xp = xbase + (k0 + j) * XS_STRIDE;
                    float4 xa = *(const float4*)xp;
                    float4 xb = *(const float4*)(xp + 4);
                    float xv[8];
                    *(float4*)&xv[0] = xa;
                    *(float4*)&xv[4] = xb;
#pragma unroll
                    for (int i = 0; i < 8; i++) {
                        acc[i].x = fmaf(xv[i], w[j].x, acc[i].x);
                        acc[i].y = fmaf(xv[i], w[j].y, acc[i].y);
                        acc[i].z = fmaf(xv[i], w[j].z, acc[i].z);
                        acc[i].w = fmaf(xv[i], w[j].w, acc[i].w);
                    }
                }
            }
        }
        float4 bv = *(const float4*)(p.c2b + 4 * tx);
#pragma unroll
        for (int i = 0; i < 8; i++) {
            acc[i].x = fmaxf(acc[i].x + bv.x, 0.f);
            acc[i].y = fmaxf(acc[i].y + bv.y, 0.f);
            acc[i].z = fmaxf(acc[i].z + bv.z, 0.f);
            acc[i].w = fmaxf(acc[i].w + bv.w, 0.f);
        }
        __syncthreads();
        float* x2s = smem;
        float* sred = smem + 32 * X2_STRIDE;
        float4 csum = make_float4(0.f, 0.f, 0.f, 0.f);
#pragma unroll
        for (int i = 0; i < 8; i++) {
            int r = ty * 8 + i;
            *(float4*)(x2s + r * X2_STRIDE + 4 * tx) = acc[i];
            if (n0 + r < p.N) {
                csum.x += acc[i].x; csum.y += acc[i].y;
                csum.z += acc[i].z; csum.w += acc[i].w;
            }
        }
        *(float4*)(sred + ty * HID + 4 * tx) = csum;
        __syncthreads();
        {
            float s = sred[0 * HID + tid] + sred[1 * HID + tid]
                    + sred[2 * HID + tid] + sred[3 * HID + tid];
            atomicAdd(&p.gsum[tid], s);
        }
        // phase 2
        float4 acc2[8];
#pragma unroll
        for (int i = 0; i < 8; i++) acc2[i] = make_float4(0.f, 0.f, 0.f, 0.f);
        {
            const float* Wc = p.aw1 + 4 * tx;
            const float* xbase = x2s + (ty * 8) * X2_STRIDE;
            for (int k0 = 0; k0 < HID; k0 += 4) {
                float4 w[4];
#pragma unroll
                for (int j = 0; j < 4; j++) w[j] = *(const float4*)(Wc + (size_t)(k0 + j) * HID);
                float4 xr[8];
#pragma unroll
                for (int i = 0; i < 8; i++) xr[i] = *(const float4*)(xbase + i * X2_STRIDE + k0);
#pragma unroll
                for (int i = 0; i < 8; i++) {
                    acc2[i].x = fmaf(xr[i].x, w[0].x, acc2[i].x);
                    acc2[i].y = fmaf(xr[i].x, w[0].y, acc2[i].y);
                    acc2[i].z = fmaf(xr[i].x, w[0].z, acc2[i].z);
                    acc2[i].w = fmaf(xr[i].x, w[0].w, acc2[i].w);
                    acc2[i].x = fmaf(xr[i].y, w[1].x, acc2[i].x);
                    acc2[i].y = fmaf(xr[i].y, w[1].y, acc2[i].y);
                    acc2[i].z = fmaf(xr[i].y, w[1].z, acc2[i].z);
                    acc2[i].w = fmaf(xr[i].y, w[1].w, acc2[i].w);
                    acc2[i].x = fmaf(xr[i].z, w[2].x, acc2[i].x);
                    acc2[i].y = fmaf(xr[i].z, w[2].y, acc2[i].y);
                    acc2[i].z = fmaf(xr[i].z, w[2].z, acc2[i].z);
                    acc2[i].w = fmaf(xr[i].z, w[2].w, acc2[i].w);
                    acc2[i].x = fmaf(xr[i].w, w[3].x, acc2[i].x);
                    acc2[i].y = fmaf(xr[i].w, w[3].y, acc2[i].y);
                    acc2[i].z = fmaf(xr[i].w, w[3].z, acc2[i].z);
                    acc2[i].w = fmaf(xr[i].w, w[3].w, acc2[i].w);
                }
            }
        }
#pragma unroll
        for (int i = 0; i < 8; i++) {
            int n = n0 + ty * 8 + i;
            if (n < p.N) *(float4*)(p.P + (size_t)n * HID + 4 * tx) = acc2[i];
        }
        __syncthreads();  // protect smem before next tile's staging
    }
}

// ---------- stage: heads (block 0 gbias, block 1 critic), 256 threads
__device__ __forceinline__ void dev_heads(const GP& p, float* smem) {
    int t = threadIdx.x;
    if (blockIdx.x == 0) {
        float s = p.ab1[t];
        for (int j = 0; j < HID; j++) s += p.gsum[j] * p.invN * p.aw1[(HID + j) * HID + t];
        p.gbias[t] = s;
        return;
    }
    if (blockIdx.x != 1) return;
    float* sp = smem;            // [512]
    float* sc1 = smem + 512;     // [512]
    float* sc2 = smem + 1024;    // [256]
    float g = p.gsum[t] * p.invN;
    sp[t] = g;
    sp[t + 256] = g;
    __syncthreads();
    for (int i = t; i < 2 * HID; i += 256) {
        float s = p.cb1[i];
        for (int k = 0; k < 2 * HID; k++) s += sp[k] * p.cw1[k * 2 * HID + i];
        sc1[i] = fmaxf(s, 0.f);
    }
    __syncthreads();
    {
        float s2 = p.cb2[t];
        for (int k = 0; k < 2 * HID; k++) s2 += sc1[k] * p.cw2[k * HID + t];
        sc2[t] = fmaxf(s2, 0.f) * p.cw3[t];
    }
    __syncthreads();
    for (int st = 128; st > 0; st >>= 1) {
        if (t < st) sc2[t] += sc2[t + st];
        __syncthreads();
    }
    if (t == 0) p.out[p.N] = sc2[0] + p.cb3[0];
}

// ---------- stage: logits
__device__ __forceinline__ void dev_logits(const GP& p) {
    int lane = threadIdx.x & 63;
    int wv = threadIdx.x >> 6;
    float4 gb = *(const float4*)(p.gbias + 4 * lane);
    float4 w2 = *(const float4*)(p.aw2 + 4 * lane);
    float b2 = p.ab2[0];
    int ngrp = (p.N + 3) / 4;
    for (int grp = blockIdx.x; grp < ngrp; grp += gridDim.x) {
        int n = grp * 4 + wv;
        if (n >= p.N) continue;
        float4 pv = *(const float4*)(p.P + (size_t)n * HID + 4 * lane);
        float v = fmaxf(pv.x + gb.x, 0.f) * w2.x
                + fmaxf(pv.y + gb.y, 0.f) * w2.y
                + fmaxf(pv.z + gb.z, 0.f) * w2.z
                + fmaxf(pv.w + gb.w, 0.f) * w2.w;
#pragma unroll
        for (int off = 32; off > 0; off >>= 1) v += __shfl_down(v, off, 64);
        if (lane == 0) p.out[n] = v + b2;
    }
}

// ================= single cooperative kernel =================
__global__ __launch_bounds__(256, 4) void k_mono(GP p) {
    __shared__ __align__(16) float smem[SMEM_FLOATS];
    cg::grid_group g = cg::this_grid();
    dev_init(p);     g.sync();
    dev_edge(p, smem); g.sync();
    dev_dinv(p);     g.sync();
    dev_scan_a(p, smem); g.sync();
    dev_scan_b(p, smem); g.sync();
    dev_scan_c(p);   g.sync();
    dev_fill(p);     g.sync();
    dev_agg3(p);     g.sync();
    dev_gather(p);   g.sync();
    dev_gemm(p, smem); g.sync();
    dev_heads(p, smem); g.sync();
    dev_logits(p);
}

// ================= fallback wrappers (multi-dispatch path) =================
__global__ void kf_init(GP p)   { dev_init(p); }
__global__ void kf_edge(GP p)   { __shared__ float s[128]; dev_edge(p, s); }
__global__ void kf_dinv(GP p)   { dev_dinv(p); }
__global__ void kf_scan_a(GP p) { __shared__ float s[256]; dev_scan_a(p, s); }
__global__ void kf_scan_b(GP p) { __shared__ float s[256]; dev_scan_b(p, s); }
__global__ void kf_scan_c(GP p) { dev_scan_c(p); }
__global__ void kf_fill(GP p)   { dev_fill(p); }
__global__ void kf_agg3(GP p)   { dev_agg3(p); }
__global__ void kf_gather(GP p) { dev_gather(p); }
__global__ __launch_bounds__(256, 4) void kf_gemm(GP p) {
    __shared__ __align__(16) float s[SMEM_FLOATS]; dev_gemm(p, s);
}
__global__ void kf_heads(GP p)  { __shared__ float s[1280]; dev_heads(p, s); }
__global__ void kf_logits(GP p) { dev_logits(p); }

extern "C" void kernel_launch(void* const* d_in, const int* in_sizes, int n_in,
                              void* d_out, int out_size, void* d_ws, size_t ws_size,
                              hipStream_t stream) {
    GP p;
    p.nf      = (const float*)d_in[0];
    p.ei      = (const int*)d_in[1];
    p.eid     = (const int*)d_in[2];
    p.epos    = (const int*)d_in[3];
    p.id_emb  = (const float*)d_in[4];
    p.pos_emb = (const float*)d_in[5];
    p.ew_w1   = (const float*)d_in[6];
    p.ew_b1   = (const float*)d_in[7];
    p.ew_w2   = (const float*)d_in[8];
    p.ew_b2   = (const float*)d_in[9];
    p.c1w     = (const float*)d_in[10];
    p.c1b     = (const float*)d_in[11];
    p.c2w     = (const float*)d_in[12];
    p.c2b     = (const float*)d_in[13];
    p.aw1     = (const float*)d_in[14];
    p.ab1     = (const float*)d_in[15];
    p.aw2     = (const float*)d_in[16];
    p.ab2     = (const float*)d_in[17];
    p.cw1     = (const float*)d_in[18];
    p.cb1     = (const float*)d_in[19];
    p.cw2     = (const float*)d_in[20];
    p.cb2     = (const float*)d_in[21];
    p.cw3     = (const float*)d_in[22];
    p.cb3     = (const float*)d_in[23];

    int N = in_sizes[0] / 3;
    int E = in_sizes[2];
    p.N = N;
    p.E = E;
    p.NB = (N + 255) / 256;
    p.invN = 1.f / (float)N;

    char* ws = (char*)d_ws;
    p.deg     = (float*)ws;  ws += (size_t)N * 4;
    p.cnt     = (int*)ws;    ws += (size_t)N * 4;
    p.gsum    = (float*)ws;  ws += HID * 4;
    p.A       = (float*)ws;  ws += (size_t)N * HID * 4;
    p.P       = (float*)ws;  ws += (size_t)N * HID * 4;
    p.ew      = (float*)ws;  ws += (size_t)E * 4;
    p.csr     = (int2*)ws;   ws += (size_t)E * 8;
    p.row_ptr = (int*)ws;    ws += (size_t)(N + 1) * 4;
    p.cursor  = (int*)ws;    ws += (size_t)N * 4;
    p.bsums   = (int*)ws;    ws += 256 * 4;
    p.bscan   = (int*)ws;    ws += 256 * 4;
    p.nf4     = (float4*)ws; ws += (size_t)N * 16;
    p.T3      = (float4*)ws; ws += (size_t)N * 16;
    p.gbias   = (float*)ws;  ws += HID * 4;
    p.out     = (float*)d_out;

    // --- try single cooperative kernel: 1024 blocks (4/CU: 37.4KB LDS, <=128 VGPR)
    void* kargs[] = { (void*)&p };
    hipError_t err = hipLaunchCooperativeKernel((const void*)k_mono, dim3(1024), dim3(256),
                                                kargs, 0, stream);
    if (err == hipSuccess) return;

    // --- fallback: multi-dispatch path (same device code)
    kf_init<<<(2 * N + HID + 255) / 256, 256, 0, stream>>>(p);
    kf_edge<<<(E + 255) / 256, 256, 0, stream>>>(p);
    kf_dinv<<<(N + 255) / 256, 256, 0, stream>>>(p);
    kf_scan_a<<<p.NB, 256, 0, stream>>>(p);
    kf_scan_b<<<1, 256, 0, stream>>>(p);
    kf_scan_c<<<p.NB, 256, 0, stream>>>(p);
    kf_fill<<<(E + 255) / 256, 256, 0, stream>>>(p);
    kf_agg3<<<(N + 255) / 256, 256, 0, stream>>>(p);
    kf_gather<<<(N + 3) / 4, 256, 0, stream>>>(p);
    kf_gemm<<<(N + 31) / 32, 256, 0, stream>>>(p);
    kf_heads<<<2, 256, 0, stream>>>(p);
    kf_logits<<<(N + 3) / 4, 256, 0, stream>>>(p);
}

// Round 11
// 546.041 us; speedup vs baseline: 3.4677x; 3.4677x over previous
//
#include <hip/hip_runtime.h>
#include <math.h>

#define HID 256

// ---------- edge weight MLP: ew = sigmoid(relu([id_emb|pos_emb] @ W1 + b1) @ W2 + b2)
// also accumulates deg[dst] += ew (float) and cnt[dst]++ (int) — both zeroed first
__global__ void k_edge(const int* __restrict__ eid, const int* __restrict__ epos,
                       const float* __restrict__ id_emb, const float* __restrict__ pos_emb,
                       const float* __restrict__ w1, const float* __restrict__ b1,
                       const float* __restrict__ w2, const float* __restrict__ b2,
                       const int* __restrict__ ei, float* __restrict__ ew,
                       float* __restrict__ deg, int* __restrict__ cnt, int E) {
    __shared__ float sW1[100];
    __shared__ float sB1[10];
    __shared__ float sW2[10];
    __shared__ float sB2;
    int t = threadIdx.x;
    if (t < 100) sW1[t] = w1[t];
    if (t < 10) { sB1[t] = b1[t]; sW2[t] = w2[t]; }
    if (t == 0) sB2 = b2[0];
    __syncthreads();
    int e = blockIdx.x * blockDim.x + t;
    if (e >= E) return;
    int id = eid[e];
    int p  = epos[e];
    const float4* ide = (const float4*)(id_emb + (size_t)id * 8);
    float4 fa = ide[0], fb = ide[1];
    float f[10];
    f[0] = fa.x; f[1] = fa.y; f[2] = fa.z; f[3] = fa.w;
    f[4] = fb.x; f[5] = fb.y; f[6] = fb.z; f[7] = fb.w;
    f[8] = pos_emb[p * 2 + 0];
    f[9] = pos_emb[p * 2 + 1];
    float acc = sB2;
#pragma unroll
    for (int j = 0; j < 10; j++) {
        float h = sB1[j];
#pragma unroll
        for (int i = 0; i < 10; i++) h += f[i] * sW1[i * 10 + j];
        h = fmaxf(h, 0.f);
        acc += h * sW2[j];
    }
    float w = 1.f / (1.f + expf(-acc));
    ew[e] = w;
    int dst = ei[E + e];
    atomicAdd(&deg[dst], w);
    atomicAdd(&cnt[dst], 1);
}

// ---------- scan phase a (196 blocks): per-256-chunk exclusive scan of cnt;
// also dinv = 1/sqrt(deg+1) and pack nf -> nf4 (same grid shape, saves a launch)
__global__ void k_scan_a(const int* __restrict__ cnt, int* __restrict__ row_ptr,
                         int* __restrict__ bsums,
                         float* __restrict__ deg, const float* __restrict__ nf,
                         float4* __restrict__ nf4, int N) {
    __shared__ int s[256];
    int b = blockIdx.x, t = threadIdx.x;
    int i = b * 256 + t;
    if (i < N) {
        deg[i] = 1.f / sqrtf(deg[i] + 1.f);
        nf4[i] = make_float4(nf[i * 3 + 0], nf[i * 3 + 1], nf[i * 3 + 2], 0.f);
    }
    int v = (i < N) ? cnt[i] : 0;
    s[t] = v;
    __syncthreads();
    for (int off = 1; off < 256; off <<= 1) {
        int u = (t >= off) ? s[t - off] : 0;
        __syncthreads();
        s[t] += u;
        __syncthreads();
    }
    int incl = s[t];
    if (i < N) row_ptr[i] = incl - v;       // local exclusive
    if (t == 255) bsums[b] = incl;          // block total
}

// ---------- scan phase b (1 block): scan block sums (NB<=256)
__global__ void k_scan_b(const int* __restrict__ bsums, int* __restrict__ bscan,
                         int* __restrict__ row_ptr, int N, int NB) {
    __shared__ int s[256];
    int t = threadIdx.x;
    int v = (t < NB) ? bsums[t] : 0;
    s[t] = v;
    __syncthreads();
    for (int off = 1; off < 256; off <<= 1) {
        int u = (t >= off) ? s[t - off] : 0;
        __syncthreads();
        s[t] += u;
        __syncthreads();
    }
    if (t < NB) bscan[t] = s[t] - v;
    if (t == 255) row_ptr[N] = s[255];      // grand total
}

// ---------- scan phase c (196 blocks): add block offsets; copy to cursor
__global__ void k_scan_c(int* __restrict__ row_ptr, int* __restrict__ cursor,
                         const int* __restrict__ bscan, int N) {
    int b = blockIdx.x, t = threadIdx.x;
    int i = b * 256 + t;
    if (i < N) {
        int rp = row_ptr[i] + bscan[b];
        row_ptr[i] = rp;
        cursor[i] = rp;
    }
}

// ---------- fill CSR: slot = cursor[dst]++; csr[slot] = {src, bitcast(norm)}
__global__ void k_fill(const int* __restrict__ ei, const float* __restrict__ ew,
                       const float* __restrict__ dinv, int* __restrict__ cursor,
                       int2* __restrict__ csr, int E) {
    int e = blockIdx.x * blockDim.x + threadIdx.x;
    if (e >= E) return;
    int src = ei[e];
    int dst = ei[E + e];
    int slot = atomicAdd(&cursor[dst], 1);
    float norm = dinv[src] * ew[e] * dinv[dst];
    csr[slot] = make_int2(src, __float_as_int(norm));
}

// ---------- layer-1 aggregation on RAW packed features, one thread per node
__global__ void k_agg3(const int* __restrict__ row_ptr, const int2* __restrict__ csr,
                       const float4* __restrict__ nf4, const float* __restrict__ dinv,
                       float4* __restrict__ T3, int N) {
    int n = blockIdx.x * blockDim.x + threadIdx.x;
    if (n >= N) return;
    int s = row_ptr[n];
    int e = row_ptr[n + 1];
    float ax = 0.f, ay = 0.f, az = 0.f;
    for (int i = s; i < e; i++) {
        int2 sn = csr[i];
        float w = __int_as_float(sn.y);
        float4 v = nf4[sn.x];
        ax = fmaf(w, v.x, ax);
        ay = fmaf(w, v.y, ay);
        az = fmaf(w, v.z, az);
    }
    float d = dinv[n];
    float dd = d * d;
    float4 v = nf4[n];
    ax = fmaf(dd, v.x, ax);
    ay = fmaf(dd, v.y, ay);
    az = fmaf(dd, v.z, az);
    T3[n] = make_float4(ax, ay, az, 0.f);
}

// ---------- fused layer-2 aggregation: recompute x1 on the fly from T3 (16B/node)
__global__ void k_gatherfused(const int* __restrict__ row_ptr, const int2* __restrict__ csr,
                              const float4* __restrict__ T3, const float* __restrict__ dinv,
                              const float* __restrict__ cw, const float* __restrict__ cb,
                              float* __restrict__ A, int N) {
    int lane = threadIdx.x & 63;
    int wv = threadIdx.x >> 6;
    int n = blockIdx.x * 4 + wv;
    if (n >= N) return;
    const float4 w0 = *(const float4*)(cw + 4 * lane);
    const float4 w1 = *(const float4*)(cw + HID + 4 * lane);
    const float4 w2 = *(const float4*)(cw + 2 * HID + 4 * lane);
    const float4 bv = *(const float4*)(cb + 4 * lane);
    int s = row_ptr[n];
    int e = row_ptr[n + 1];
    float4 acc = make_float4(0.f, 0.f, 0.f, 0.f);
    for (int i = s; i < e; i++) {
        int2 sn = csr[i];
        float w = __int_as_float(sn.y);
        float4 t = T3[sn.x];
        float xx = fmaxf(fmaf(t.x, w0.x, fmaf(t.y, w1.x, fmaf(t.z, w2.x, bv.x))), 0.f);
        float xy = fmaxf(fmaf(t.x, w0.y, fmaf(t.y, w1.y, fmaf(t.z, w2.y, bv.y))), 0.f);
        float xz = fmaxf(fmaf(t.x, w0.z, fmaf(t.y, w1.z, fmaf(t.z, w2.z, bv.z))), 0.f);
        float xw = fmaxf(fmaf(t.x, w0.w, fmaf(t.y, w1.w, fmaf(t.z, w2.w, bv.w))), 0.f);
        acc.x = fmaf(w, xx, acc.x);
        acc.y = fmaf(w, xy, acc.y);
        acc.z = fmaf(w, xz, acc.z);
        acc.w = fmaf(w, xw, acc.w);
    }
    float d = dinv[n];
    float dd = d * d;
    float4 t = T3[n];
    float xx = fmaxf(fmaf(t.x, w0.x, fmaf(t.y, w1.x, fmaf(t.z, w2.x, bv.x))), 0.f);
    float xy = fmaxf(fmaf(t.x, w0.y, fmaf(t.y, w1.y, fmaf(t.z, w2.y, bv.y))), 0.f);
    float xz = fmaxf(fmaf(t.x, w0.z, fmaf(t.y, w1.z, fmaf(t.z, w2.z, bv.z))), 0.f);
    float xw = fmaxf(fmaf(t.x, w0.w, fmaf(t.y, w1.w, fmaf(t.z, w2.w, bv.w))), 0.f);
    acc.x = fmaf(dd, xx, acc.x);
    acc.y = fmaf(dd, xy, acc.y);
    acc.z = fmaf(dd, xz, acc.z);
    acc.w = fmaf(dd, xw, acc.w);
    *(float4*)(A + (size_t)n * HID + lane * 4) = acc;
}

// ================= fused double GEMM, 32-row tile, 8x4 register blocking (proven R7 body)
#define XS_STRIDE 36
#define X2_STRIDE 260
#define SMEM_FLOATS 9344

__global__ __launch_bounds__(256, 4) void k_gemm_fused(
        const float* __restrict__ A, const float* __restrict__ W2,
        const float* __restrict__ b2, const float* __restrict__ aw1,
        float* __restrict__ P, float* __restrict__ gsum, int N) {
    __shared__ __align__(16) float smem[SMEM_FLOATS];
    int tid = threadIdx.x;
    int n0 = blockIdx.x * 32;

    // --- stage A tile transposed: xsT[col*36 + r]
    {
        int r = tid >> 3;
        int c8 = tid & 7;
        int n = n0 + r;
#pragma unroll
        for (int j = 0; j < 8; j++) {
            int c4 = c8 + 8 * j;
            float4 v = make_float4(0.f, 0.f, 0.f, 0.f);
            if (n < N) v = *(const float4*)(A + (size_t)n * HID + 4 * c4);
            int col = 4 * c4;
            smem[(col + 0) * XS_STRIDE + r] = v.x;
            smem[(col + 1) * XS_STRIDE + r] = v.y;
            smem[(col + 2) * XS_STRIDE + r] = v.z;
            smem[(col + 3) * XS_STRIDE + r] = v.w;
        }
    }
    __syncthreads();

    int tx = tid & 63;
    int ty = tid >> 6;

    // --- phase 1: x2 tile = relu(A@W2 + b2), k-unroll 8 with batched W loads
    float4 acc[8];
#pragma unroll
    for (int i = 0; i < 8; i++) acc[i] = make_float4(0.f, 0.f, 0.f, 0.f);
    {
        const float* Wc = W2 + 4 * tx;
        const float* xbase = &smem[ty * 8];
        for (int k0 = 0; k0 < HID; k0 += 8) {
            float4 w[8];
#pragma unroll
            for (int j = 0; j < 8; j++) w[j] = *(const float4*)(Wc + (size_t)(k0 + j) * HID);
#pragma unroll
            for (int j = 0; j < 8; j++) {
                const float* xp = xbase + (k0 + j) * XS_STRIDE;
                float4 xa = *(const float4*)xp;
                float4 xb = *(const float4*)(xp + 4);
                float xv[8];
                *(float4*)&xv[0] = xa;
                *(float4*)&xv[4] = xb;
#pragma unroll
                for (int i = 0; i < 8; i++) {
                    acc[i].x = fmaf(xv[i], w[j].x, acc[i].x);
                    acc[i].y = fmaf(xv[i], w[j].y, acc[i].y);
                    acc[i].z = fmaf(xv[i], w[j].z, acc[i].z);
                    acc[i].w = fmaf(xv[i], w[j].w, acc[i].w);
                }
            }
        }
    }
    float4 bv = *(const float4*)(b2 + 4 * tx);
#pragma unroll
    for (int i = 0; i < 8; i++) {
        acc[i].x = fmaxf(acc[i].x + bv.x, 0.f);
        acc[i].y = fmaxf(acc[i].y + bv.y, 0.f);
        acc[i].z = fmaxf(acc[i].z + bv.z, 0.f);
        acc[i].w = fmaxf(acc[i].w + bv.w, 0.f);
    }
    __syncthreads();  // done reading xsT; smem becomes x2s + sred

    float* x2s = smem;
    float* sred = smem + 32 * X2_STRIDE;

    // --- write x2 tile row-major; per-thread colsum over valid rows
    float4 csum = make_float4(0.f, 0.f, 0.f, 0.f);
#pragma unroll
    for (int i = 0; i < 8; i++) {
        int r = ty * 8 + i;
        *(float4*)(x2s + r * X2_STRIDE + 4 * tx) = acc[i];
        if (n0 + r < N) {
            csum.x += acc[i].x; csum.y += acc[i].y;
            csum.z += acc[i].z; csum.w += acc[i].w;
        }
    }
    *(float4*)(sred + ty * HID + 4 * tx) = csum;
    __syncthreads();
    {
        float s = sred[0 * HID + tid] + sred[1 * HID + tid]
                + sred[2 * HID + tid] + sred[3 * HID + tid];
        atomicAdd(&gsum[tid], s);
    }

    // --- phase 2: P = x2 @ aw1_top, k-unroll 4 (x2 rows broadcast from LDS)
    float4 acc2[8];
#pragma unroll
    for (int i = 0; i < 8; i++) acc2[i] = make_float4(0.f, 0.f, 0.f, 0.f);
    {
        const float* Wc = aw1 + 4 * tx;
        const float* xbase = x2s + (ty * 8) * X2_STRIDE;
        for (int k0 = 0; k0 < HID; k0 += 4) {
            float4 w[4];
#pragma unroll
            for (int j = 0; j < 4; j++) w[j] = *(const float4*)(Wc + (size_t)(k0 + j) * HID);
            float4 xr[8];
#pragma unroll
            for (int i = 0; i < 8; i++) xr[i] = *(const float4*)(xbase + i * X2_STRIDE + k0);
#pragma unroll
            for (int i = 0; i < 8; i++) {
                acc2[i].x = fmaf(xr[i].x, w[0].x, acc2[i].x);
                acc2[i].y = fmaf(xr[i].x, w[0].y, acc2[i].y);
                acc2[i].z = fmaf(xr[i].x, w[0].z, acc2[i].z);
                acc2[i].w = fmaf(xr[i].x, w[0].w, acc2[i].w);
                acc2[i].x = fmaf(xr[i].y, w[1].x, acc2[i].x);
                acc2[i].y = fmaf(xr[i].y, w[1].y, acc2[i].y);
                acc2[i].z = fmaf(xr[i].y, w[1].z, acc2[i].z);
                acc2[i].w = fmaf(xr[i].y, w[1].w, acc2[i].w);
                acc2[i].x = fmaf(xr[i].z, w[2].x, acc2[i].x);
                acc2[i].y = fmaf(xr[i].z, w[2].y, acc2[i].y);
                acc2[i].z = fmaf(xr[i].z, w[2].z, acc2[i].z);
                acc2[i].w = fmaf(xr[i].z, w[2].w, acc2[i].w);
                acc2[i].x = fmaf(xr[i].w, w[3].x, acc2[i].x);
                acc2[i].y = fmaf(xr[i].w, w[3].y, acc2[i].y);
                acc2[i].z = fmaf(xr[i].w, w[3].z, acc2[i].z);
                acc2[i].w = fmaf(xr[i].w, w[3].w, acc2[i].w);
            }
        }
    }
#pragma unroll
    for (int i = 0; i < 8; i++) {
        int n = n0 + ty * 8 + i;
        if (n < N) *(float4*)(P + (size_t)n * HID + 4 * tx) = acc2[i];
    }
}

// ---------- logits epilogue: out[n] = relu(P[n,:] + gbias) @ aw2 + ab2
__global__ void k_logits(const float* __restrict__ P, const float* __restrict__ gbias,
                         const float* __restrict__ aw2, const float* __restrict__ ab2,
                         float* __restrict__ out, int N) {
    int lane = threadIdx.x & 63;
    int wv = threadIdx.x >> 6;
    int n = blockIdx.x * 4 + wv;
    if (n >= N) return;
    float4 p = *(const float4*)(P + (size_t)n * HID + 4 * lane);
    float4 gb = *(const float4*)(gbias + 4 * lane);
    float4 w2 = *(const float4*)(aw2 + 4 * lane);
    float v = fmaxf(p.x + gb.x, 0.f) * w2.x
            + fmaxf(p.y + gb.y, 0.f) * w2.y
            + fmaxf(p.z + gb.z, 0.f) * w2.z
            + fmaxf(p.w + gb.w, 0.f) * w2.w;
#pragma unroll
    for (int off = 32; off > 0; off >>= 1) v += __shfl_down(v, off, 64);
    if (lane == 0) out[n] = v + ab2[0];
}

// ---------- merged head prep: block 0 -> gbias, block 1 -> critic value
__global__ void k_heads(const float* __restrict__ gsum,
                        const float* __restrict__ aw1, const float* __restrict__ ab1,
                        float* __restrict__ gbias,
                        const float* __restrict__ cw1, const float* __restrict__ cb1,
                        const float* __restrict__ cw2, const float* __restrict__ cb2,
                        const float* __restrict__ cw3, const float* __restrict__ cb3,
                        float* __restrict__ sv_out, float invN) {
    int t = threadIdx.x;  // 512
    if (blockIdx.x == 0) {
        if (t < HID) {
            float s = ab1[t];
            for (int j = 0; j < HID; j++) s += gsum[j] * invN * aw1[(HID + j) * HID + t];
            gbias[t] = s;
        }
        return;
    }
    __shared__ float p[2 * HID];
    __shared__ float c1[2 * HID];
    __shared__ float c2[HID];
    p[t] = gsum[t & (HID - 1)] * invN;
    __syncthreads();
    float s = cb1[t];
    for (int i = 0; i < 2 * HID; i++) s += p[i] * cw1[i * 2 * HID + t];
    c1[t] = fmaxf(s, 0.f);
    __syncthreads();
    if (t < HID) {
        float s2 = cb2[t];
        for (int i = 0; i < 2 * HID; i++) s2 += c1[i] * cw2[i * HID + t];
        c2[t] = fmaxf(s2, 0.f) * cw3[t];
    }
    __syncthreads();
    for (int st = HID / 2; st > 0; st >>= 1) {
        if (t < st) c2[t] += c2[t + st];
        __syncthreads();
    }
    if (t == 0) sv_out[0] = c2[0] + cb3[0];
}

extern "C" void kernel_launch(void* const* d_in, const int* in_sizes, int n_in,
                              void* d_out, int out_size, void* d_ws, size_t ws_size,
                              hipStream_t stream) {
    const float* nf      = (const float*)d_in[0];
    const int*   ei      = (const int*)d_in[1];
    const int*   eid     = (const int*)d_in[2];
    const int*   epos    = (const int*)d_in[3];
    const float* id_emb  = (const float*)d_in[4];
    const float* pos_emb = (const float*)d_in[5];
    const float* ew_w1   = (const float*)d_in[6];
    const float* ew_b1   = (const float*)d_in[7];
    const float* ew_w2   = (const float*)d_in[8];
    const float* ew_b2   = (const float*)d_in[9];
    const float* c1w     = (const float*)d_in[10];
    const float* c1b     = (const float*)d_in[11];
    const float* c2w     = (const float*)d_in[12];
    const float* c2b     = (const float*)d_in[13];
    const float* aw1     = (const float*)d_in[14];
    const float* ab1     = (const float*)d_in[15];
    const float* aw2     = (const float*)d_in[16];
    const float* ab2     = (const float*)d_in[17];
    const float* cw1     = (const float*)d_in[18];
    const float* cb1     = (const float*)d_in[19];
    const float* cw2     = (const float*)d_in[20];
    const float* cb2     = (const float*)d_in[21];
    const float* cw3     = (const float*)d_in[22];
    const float* cb3     = (const float*)d_in[23];

    int N = in_sizes[0] / 3;
    int E = in_sizes[2];
    int NB = (N + 255) / 256;
    float invN = 1.f / (float)N;

    char* ws = (char*)d_ws;
    // deg | cnt | gsum contiguous -> single memset
    float* deg      = (float*)ws;                         ws += (size_t)N * 4;
    int*   cnt      = (int*)ws;                           ws += (size_t)N * 4;
    float* gsum     = (float*)ws;                         ws += HID * 4;
    float* A        = (float*)ws;                         ws += (size_t)N * HID * 4;
    float* P        = (float*)ws;                         ws += (size_t)N * HID * 4;
    float* ew       = (float*)ws;                         ws += (size_t)E * 4;
    int2*  csr      = (int2*)ws;                          ws += (size_t)E * 8;
    int*   row_ptr  = (int*)ws;                           ws += (size_t)(N + 1) * 4;
    int*   cursor   = (int*)ws;                           ws += (size_t)N * 4;
    int*   bsums    = (int*)ws;                           ws += 256 * 4;
    int*   bscan    = (int*)ws;                           ws += 256 * 4;
    float4* T3      = (float4*)ws;                        ws += (size_t)N * 16;
    float4* nf4     = (float4*)ws;                        ws += (size_t)N * 16;
    float* gbias    = (float*)ws;                         ws += HID * 4;

    float* out = (float*)d_out;  // [N] logits + [1] state value

    // --- zero deg+cnt+gsum in one memset
    hipMemsetAsync(deg, 0, (size_t)(2 * N + HID) * sizeof(float), stream);

    // --- edge MLP + degree + histogram
    k_edge<<<(E + 255) / 256, 256, 0, stream>>>(eid, epos, id_emb, pos_emb,
                                                ew_w1, ew_b1, ew_w2, ew_b2, ei, ew, deg, cnt, E);

    // --- parallel 3-phase scan (+ dinv + nf4 pack folded into phase a)
    k_scan_a<<<NB, 256, 0, stream>>>(cnt, row_ptr, bsums, deg, nf, nf4, N);
    k_scan_b<<<1, 256, 0, stream>>>(bsums, bscan, row_ptr, N, NB);
    k_scan_c<<<NB, 256, 0, stream>>>(row_ptr, cursor, bscan, N);

    // --- fill CSR
    k_fill<<<(E + 255) / 256, 256, 0, stream>>>(ei, ew, deg, cursor, csr, E);

    // --- layer 1 aggregate on raw features (16B/node)
    k_agg3<<<(N + 255) / 256, 256, 0, stream>>>(row_ptr, csr, nf4, deg, T3, N);

    // --- layer 2 aggregate with x1 recomputed on the fly
    k_gatherfused<<<(N + 3) / 4, 256, 0, stream>>>(row_ptr, csr, T3, deg, c1w, c1b, A, N);

    // --- fused conv2-GEMM + actor-GEMM (+ colsum); x2 stays on-chip
    k_gemm_fused<<<(N + 31) / 32, 256, 0, stream>>>(A, c2w, c2b, aw1, P, gsum, N);

    // --- heads prep: gbias (block 0) + critic value (block 1, writes out[N])
    k_heads<<<2, 2 * HID, 0, stream>>>(gsum, aw1, ab1, gbias,
                                       cw1, cb1, cw2, cb2, cw3, cb3, out + N, invN);

    // --- logits epilogue (writes out[0..N))
    k_logits<<<(N + 3) / 4, 256, 0, stream>>>(P, gbias, aw2, ab2, out, N);
}

// Round 12
// 529.842 us; speedup vs baseline: 3.5737x; 1.0306x over previous
//
#include <hip/hip_runtime.h>
#include <math.h>

#define HID 256

typedef __attribute__((ext_vector_type(8))) short short8;
typedef __attribute__((ext_vector_type(4))) float floatx4;

__device__ __forceinline__ ushort bf16_rne(float x) {
    uint u = __float_as_uint(x);
    uint r = (u + 0x7FFFu + ((u >> 16) & 1u)) >> 16;
    return (ushort)r;
}
__device__ __forceinline__ float bf16_to_f(ushort h) {
    return __uint_as_float(((uint)h) << 16);
}

// ---------- edge weight MLP (unchanged, proven)
__global__ void k_edge(const int* __restrict__ eid, const int* __restrict__ epos,
                       const float* __restrict__ id_emb, const float* __restrict__ pos_emb,
                       const float* __restrict__ w1, const float* __restrict__ b1,
                       const float* __restrict__ w2, const float* __restrict__ b2,
                       const int* __restrict__ ei, float* __restrict__ ew,
                       float* __restrict__ deg, int* __restrict__ cnt, int E) {
    __shared__ float sW1[100];
    __shared__ float sB1[10];
    __shared__ float sW2[10];
    __shared__ float sB2;
    int t = threadIdx.x;
    if (t < 100) sW1[t] = w1[t];
    if (t < 10) { sB1[t] = b1[t]; sW2[t] = w2[t]; }
    if (t == 0) sB2 = b2[0];
    __syncthreads();
    int e = blockIdx.x * blockDim.x + t;
    if (e >= E) return;
    int id = eid[e];
    int p  = epos[e];
    const float4* ide = (const float4*)(id_emb + (size_t)id * 8);
    float4 fa = ide[0], fb = ide[1];
    float f[10];
    f[0] = fa.x; f[1] = fa.y; f[2] = fa.z; f[3] = fa.w;
    f[4] = fb.x; f[5] = fb.y; f[6] = fb.z; f[7] = fb.w;
    f[8] = pos_emb[p * 2 + 0];
    f[9] = pos_emb[p * 2 + 1];
    float acc = sB2;
#pragma unroll
    for (int j = 0; j < 10; j++) {
        float h = sB1[j];
#pragma unroll
        for (int i = 0; i < 10; i++) h += f[i] * sW1[i * 10 + j];
        h = fmaxf(h, 0.f);
        acc += h * sW2[j];
    }
    float w = 1.f / (1.f + expf(-acc));
    ew[e] = w;
    int dst = ei[E + e];
    atomicAdd(&deg[dst], w);
    atomicAdd(&cnt[dst], 1);
}

// ---------- weight prep: fragment-ordered bf16 hi/lo for W2 and aw1_top
// Frag[c][t][L][j] = W[32c + (L>>4)*8 + j][16t + (L&15)]
__global__ void k_wprep(const float* __restrict__ w2, const float* __restrict__ aw1,
                        ushort* __restrict__ w2h, ushort* __restrict__ w2l,
                        ushort* __restrict__ a1h, ushort* __restrict__ a1l) {
    int gid = blockIdx.x * 256 + threadIdx.x;    // 16384 total
    int mat = gid >> 13;
    int rem = gid & 8191;
    int c = rem >> 10;
    int t = (rem >> 6) & 15;
    int L = rem & 63;
    int k0 = 32 * c + (L >> 4) * 8;
    int n  = 16 * t + (L & 15);
    const float* W = mat ? aw1 : w2;
    ushort* H  = mat ? a1h : w2h;
    ushort* Lo = mat ? a1l : w2l;
    short8 hv, lv;
#pragma unroll
    for (int j = 0; j < 8; j++) {
        float x = W[(size_t)(k0 + j) * HID + n];
        ushort h = bf16_rne(x);
        hv[j] = (short)h;
        lv[j] = (short)bf16_rne(x - bf16_to_f(h));
    }
    size_t off = (size_t)rem * 8;
    *(short8*)(H + off) = hv;
    *(short8*)(Lo + off) = lv;
}

// ---------- scan phase a (+dinv + nf4 pack)
__global__ void k_scan_a(const int* __restrict__ cnt, int* __restrict__ row_ptr,
                         int* __restrict__ bsums,
                         float* __restrict__ deg, const float* __restrict__ nf,
                         float4* __restrict__ nf4, int N) {
    __shared__ int s[256];
    int b = blockIdx.x, t = threadIdx.x;
    int i = b * 256 + t;
    if (i < N) {
        deg[i] = 1.f / sqrtf(deg[i] + 1.f);
        nf4[i] = make_float4(nf[i * 3 + 0], nf[i * 3 + 1], nf[i * 3 + 2], 0.f);
    }
    int v = (i < N) ? cnt[i] : 0;
    s[t] = v;
    __syncthreads();
    for (int off = 1; off < 256; off <<= 1) {
        int u = (t >= off) ? s[t - off] : 0;
        __syncthreads();
        s[t] += u;
        __syncthreads();
    }
    int incl = s[t];
    if (i < N) row_ptr[i] = incl - v;
    if (t == 255) bsums[b] = incl;
}

__global__ void k_scan_b(const int* __restrict__ bsums, int* __restrict__ bscan,
                         int* __restrict__ row_ptr, int N, int NB) {
    __shared__ int s[256];
    int t = threadIdx.x;
    int v = (t < NB) ? bsums[t] : 0;
    s[t] = v;
    __syncthreads();
    for (int off = 1; off < 256; off <<= 1) {
        int u = (t >= off) ? s[t - off] : 0;
        __syncthreads();
        s[t] += u;
        __syncthreads();
    }
    if (t < NB) bscan[t] = s[t] - v;
    if (t == 255) row_ptr[N] = s[255];
}

__global__ void k_scan_c(int* __restrict__ row_ptr, int* __restrict__ cursor,
                         const int* __restrict__ bscan, int N) {
    int b = blockIdx.x, t = threadIdx.x;
    int i = b * 256 + t;
    if (i < N) {
        int rp = row_ptr[i] + bscan[b];
        row_ptr[i] = rp;
        cursor[i] = rp;
    }
}

// ---------- fill CSR
__global__ void k_fill(const int* __restrict__ ei, const float* __restrict__ ew,
                       const float* __restrict__ dinv, int* __restrict__ cursor,
                       int2* __restrict__ csr, int E) {
    int e = blockIdx.x * blockDim.x + threadIdx.x;
    if (e >= E) return;
    int src = ei[e];
    int dst = ei[E + e];
    int slot = atomicAdd(&cursor[dst], 1);
    float norm = dinv[src] * ew[e] * dinv[dst];
    csr[slot] = make_int2(src, __float_as_int(norm));
}

// ---------- layer-1 aggregation on raw packed features
__global__ void k_agg3(const int* __restrict__ row_ptr, const int2* __restrict__ csr,
                       const float4* __restrict__ nf4, const float* __restrict__ dinv,
                       float4* __restrict__ T3, int N) {
    int n = blockIdx.x * blockDim.x + threadIdx.x;
    if (n >= N) return;
    int s = row_ptr[n];
    int e = row_ptr[n + 1];
    float ax = 0.f, ay = 0.f, az = 0.f;
    for (int i = s; i < e; i++) {
        int2 sn = csr[i];
        float w = __int_as_float(sn.y);
        float4 v = nf4[sn.x];
        ax = fmaf(w, v.x, ax);
        ay = fmaf(w, v.y, ay);
        az = fmaf(w, v.z, az);
    }
    float d = dinv[n];
    float dd = d * d;
    float4 v = nf4[n];
    ax = fmaf(dd, v.x, ax);
    ay = fmaf(dd, v.y, ay);
    az = fmaf(dd, v.z, az);
    T3[n] = make_float4(ax, ay, az, 0.f);
}

// ---------- fused layer-2 aggregation: recompute x1 on the fly from T3
__global__ void k_gatherfused(const int* __restrict__ row_ptr, const int2* __restrict__ csr,
                              const float4* __restrict__ T3, const float* __restrict__ dinv,
                              const float* __restrict__ cw, const float* __restrict__ cb,
                              float* __restrict__ A, int N) {
    int lane = threadIdx.x & 63;
    int wv = threadIdx.x >> 6;
    int n = blockIdx.x * 4 + wv;
    if (n >= N) return;
    const float4 w0 = *(const float4*)(cw + 4 * lane);
    const float4 w1 = *(const float4*)(cw + HID + 4 * lane);
    const float4 w2 = *(const float4*)(cw + 2 * HID + 4 * lane);
    const float4 bv = *(const float4*)(cb + 4 * lane);
    int s = row_ptr[n];
    int e = row_ptr[n + 1];
    float4 acc = make_float4(0.f, 0.f, 0.f, 0.f);
    for (int i = s; i < e; i++) {
        int2 sn = csr[i];
        float w = __int_as_float(sn.y);
        float4 t = T3[sn.x];
        float xx = fmaxf(fmaf(t.x, w0.x, fmaf(t.y, w1.x, fmaf(t.z, w2.x, bv.x))), 0.f);
        float xy = fmaxf(fmaf(t.x, w0.y, fmaf(t.y, w1.y, fmaf(t.z, w2.y, bv.y))), 0.f);
        float xz = fmaxf(fmaf(t.x, w0.z, fmaf(t.y, w1.z, fmaf(t.z, w2.z, bv.z))), 0.f);
        float xw = fmaxf(fmaf(t.x, w0.w, fmaf(t.y, w1.w, fmaf(t.z, w2.w, bv.w))), 0.f);
        acc.x = fmaf(w, xx, acc.x);
        acc.y = fmaf(w, xy, acc.y);
        acc.z = fmaf(w, xz, acc.z);
        acc.w = fmaf(w, xw, acc.w);
    }
    float d = dinv[n];
    float dd = d * d;
    float4 t = T3[n];
    float xx = fmaxf(fmaf(t.x, w0.x, fmaf(t.y, w1.x, fmaf(t.z, w2.x, bv.x))), 0.f);
    float xy = fmaxf(fmaf(t.x, w0.y, fmaf(t.y, w1.y, fmaf(t.z, w2.y, bv.y))), 0.f);
    float xz = fmaxf(fmaf(t.x, w0.z, fmaf(t.y, w1.z, fmaf(t.z, w2.z, bv.z))), 0.f);
    float xw = fmaxf(fmaf(t.x, w0.w, fmaf(t.y, w1.w, fmaf(t.z, w2.w, bv.w))), 0.f);
    acc.x = fmaf(dd, xx, acc.x);
    acc.y = fmaf(dd, xy, acc.y);
    acc.z = fmaf(dd, xz, acc.z);
    acc.w = fmaf(dd, xw, acc.w);
    *(float4*)(A + (size_t)n * HID + lane * 4) = acc;
}

// ================= MFMA double GEMM (bf16x2 split, 3 products):
// phase 1: x2 = relu(A @ W2 + b2)  -> colsum into gsum; x2 split to bf16 LDS
// phase 2: P = x2 @ aw1_top
// 32-row tile/block, 4 waves: wave w -> m-tile (w&1), n-tiles (w>>1)*8..+7
// LDS rows stride 264 shorts (2-way bank aliasing = free)
#define ASTRIDE 264

__global__ __launch_bounds__(256, 3) void k_gemm_mfma(
        const float* __restrict__ A, const float* __restrict__ b2,
        const ushort* __restrict__ w2h, const ushort* __restrict__ w2l,
        const ushort* __restrict__ a1h, const ushort* __restrict__ a1l,
        float* __restrict__ P, float* __restrict__ gsum, int N) {
    __shared__ ushort Hs[32 * ASTRIDE];
    __shared__ ushort Ls[32 * ASTRIDE];
    int tid = threadIdx.x;
    int n0 = blockIdx.x * 32;

    // --- stage A tile: fp32 -> bf16 hi/lo rows in LDS
    {
        int r = tid >> 3;
        int c8 = tid & 7;
        int n = n0 + r;
#pragma unroll
        for (int j = 0; j < 8; j++) {
            int c4 = c8 + 8 * j;
            float4 v = make_float4(0.f, 0.f, 0.f, 0.f);
            if (n < N) v = *(const float4*)(A + (size_t)n * HID + 4 * c4);
            ushort4 hv, lv;
            ushort h;
            h = bf16_rne(v.x); hv.x = h; lv.x = bf16_rne(v.x - bf16_to_f(h));
            h = bf16_rne(v.y); hv.y = h; lv.y = bf16_rne(v.y - bf16_to_f(h));
            h = bf16_rne(v.z); hv.z = h; lv.z = bf16_rne(v.z - bf16_to_f(h));
            h = bf16_rne(v.w); hv.w = h; lv.w = bf16_rne(v.w - bf16_to_f(h));
            int base = r * ASTRIDE + 4 * c4;
            *(ushort4*)&Hs[base] = hv;
            *(ushort4*)&Ls[base] = lv;
        }
    }
    __syncthreads();

    int w = tid >> 6;
    int L = tid & 63;
    int mt = w & 1;
    int tb = (w >> 1) * 8;
    int quad = L >> 4, ln = L & 15;
    int arow = mt * 16 + ln;

    // --- phase 1: x2 = relu(A @ W2 + b2)
    floatx4 acc[8];
#pragma unroll
    for (int i = 0; i < 8; i++) acc[i] = 0.f;
    for (int c = 0; c < 8; c++) {
        short8 ah = *(const short8*)&Hs[arow * ASTRIDE + 32 * c + quad * 8];
        short8 al = *(const short8*)&Ls[arow * ASTRIDE + 32 * c + quad * 8];
#pragma unroll
        for (int tt = 0; tt < 8; tt++) {
            size_t off = ((size_t)(c * 16 + tb + tt) * 64 + L) * 8;
            short8 bh = *(const short8*)(w2h + off);
            short8 bl = *(const short8*)(w2l + off);
            acc[tt] = __builtin_amdgcn_mfma_f32_16x16x32_bf16(ah, bh, acc[tt], 0, 0, 0);
            acc[tt] = __builtin_amdgcn_mfma_f32_16x16x32_bf16(ah, bl, acc[tt], 0, 0, 0);
            acc[tt] = __builtin_amdgcn_mfma_f32_16x16x32_bf16(al, bh, acc[tt], 0, 0, 0);
        }
    }

    // --- epilogue 1: bias + relu + colsum (C layout: col=ln, row=quad*4+reg)
#pragma unroll
    for (int tt = 0; tt < 8; tt++) {
        int col = (tb + tt) * 16 + ln;
        float bb = b2[col];
        float s = 0.f;
#pragma unroll
        for (int r = 0; r < 4; r++) {
            int row = n0 + mt * 16 + quad * 4 + r;
            float v = fmaxf(acc[tt][r] + bb, 0.f);
            acc[tt][r] = v;
            if (row < N) s += v;
        }
        s += __shfl_down(s, 32, 64);
        s += __shfl_down(s, 16, 64);
        if (L < 16) atomicAdd(&gsum[col], s);
    }
    __syncthreads();   // all phase-1 LDS reads done

    // --- split x2 to bf16 hi/lo in LDS (reuse Hs/Ls)
#pragma unroll
    for (int tt = 0; tt < 8; tt++) {
        int col = (tb + tt) * 16 + ln;
#pragma unroll
        for (int r = 0; r < 4; r++) {
            int row = mt * 16 + quad * 4 + r;
            float v = acc[tt][r];
            ushort h = bf16_rne(v);
            Hs[row * ASTRIDE + col] = h;
            Ls[row * ASTRIDE + col] = bf16_rne(v - bf16_to_f(h));
        }
    }
    __syncthreads();

    // --- phase 2: P = x2 @ aw1_top
    floatx4 acc2[8];
#pragma unroll
    for (int i = 0; i < 8; i++) acc2[i] = 0.f;
    for (int c = 0; c < 8; c++) {
        short8 ah = *(const short8*)&Hs[arow * ASTRIDE + 32 * c + quad * 8];
        short8 al = *(const short8*)&Ls[arow * ASTRIDE + 32 * c + quad * 8];
#pragma unroll
        for (int tt = 0; tt < 8; tt++) {
            size_t off = ((size_t)(c * 16 + tb + tt) * 64 + L) * 8;
            short8 bh = *(const short8*)(a1h + off);
            short8 bl = *(const short8*)(a1l + off);
            acc2[tt] = __builtin_amdgcn_mfma_f32_16x16x32_bf16(ah, bh, acc2[tt], 0, 0, 0);
            acc2[tt] = __builtin_amdgcn_mfma_f32_16x16x32_bf16(ah, bl, acc2[tt], 0, 0, 0);
            acc2[tt] = __builtin_amdgcn_mfma_f32_16x16x32_bf16(al, bh, acc2[tt], 0, 0, 0);
        }
    }

    // --- store P (C layout)
#pragma unroll
    for (int tt = 0; tt < 8; tt++) {
        int col = (tb + tt) * 16 + ln;
#pragma unroll
        for (int r = 0; r < 4; r++) {
            int row = n0 + mt * 16 + quad * 4 + r;
            if (row < N) P[(size_t)row * HID + col] = acc2[tt][r];
        }
    }
}

// ---------- logits epilogue
__global__ void k_logits(const float* __restrict__ P, const float* __restrict__ gbias,
                         const float* __restrict__ aw2, const float* __restrict__ ab2,
                         float* __restrict__ out, int N) {
    int lane = threadIdx.x & 63;
    int wv = threadIdx.x >> 6;
    int n = blockIdx.x * 4 + wv;
    if (n >= N) return;
    float4 p = *(const float4*)(P + (size_t)n * HID + 4 * lane);
    float4 gb = *(const float4*)(gbias + 4 * lane);
    float4 w2 = *(const float4*)(aw2 + 4 * lane);
    float v = fmaxf(p.x + gb.x, 0.f) * w2.x
            + fmaxf(p.y + gb.y, 0.f) * w2.y
            + fmaxf(p.z + gb.z, 0.f) * w2.z
            + fmaxf(p.w + gb.w, 0.f) * w2.w;
#pragma unroll
    for (int off = 32; off > 0; off >>= 1) v += __shfl_down(v, off, 64);
    if (lane == 0) out[n] = v + ab2[0];
}

// ---------- merged head prep
__global__ void k_heads(const float* __restrict__ gsum,
                        const float* __restrict__ aw1, const float* __restrict__ ab1,
                        float* __restrict__ gbias,
                        const float* __restrict__ cw1, const float* __restrict__ cb1,
                        const float* __restrict__ cw2, const float* __restrict__ cb2,
                        const float* __restrict__ cw3, const float* __restrict__ cb3,
                        float* __restrict__ sv_out, float invN) {
    int t = threadIdx.x;  // 512
    if (blockIdx.x == 0) {
        if (t < HID) {
            float s = ab1[t];
            for (int j = 0; j < HID; j++) s += gsum[j] * invN * aw1[(HID + j) * HID + t];
            gbias[t] = s;
        }
        return;
    }
    __shared__ float p[2 * HID];
    __shared__ float c1[2 * HID];
    __shared__ float c2[HID];
    p[t] = gsum[t & (HID - 1)] * invN;
    __syncthreads();
    float s = cb1[t];
    for (int i = 0; i < 2 * HID; i++) s += p[i] * cw1[i * 2 * HID + t];
    c1[t] = fmaxf(s, 0.f);
    __syncthreads();
    if (t < HID) {
        float s2 = cb2[t];
        for (int i = 0; i < 2 * HID; i++) s2 += c1[i] * cw2[i * HID + t];
        c2[t] = fmaxf(s2, 0.f) * cw3[t];
    }
    __syncthreads();
    for (int st = HID / 2; st > 0; st >>= 1) {
        if (t < st) c2[t] += c2[t + st];
        __syncthreads();
    }
    if (t == 0) sv_out[0] = c2[0] + cb3[0];
}

extern "C" void kernel_launch(void* const* d_in, const int* in_sizes, int n_in,
                              void* d_out, int out_size, void* d_ws, size_t ws_size,
                              hipStream_t stream) {
    const float* nf      = (const float*)d_in[0];
    const int*   ei      = (const int*)d_in[1];
    const int*   eid     = (const int*)d_in[2];
    const int*   epos    = (const int*)d_in[3];
    const float* id_emb  = (const float*)d_in[4];
    const float* pos_emb = (const float*)d_in[5];
    const float* ew_w1   = (const float*)d_in[6];
    const float* ew_b1   = (const float*)d_in[7];
    const float* ew_w2   = (const float*)d_in[8];
    const float* ew_b2   = (const float*)d_in[9];
    const float* c1w     = (const float*)d_in[10];
    const float* c1b     = (const float*)d_in[11];
    const float* c2w     = (const float*)d_in[12];
    const float* c2b     = (const float*)d_in[13];
    const float* aw1     = (const float*)d_in[14];
    const float* ab1     = (const float*)d_in[15];
    const float* aw2     = (const float*)d_in[16];
    const float* ab2     = (const float*)d_in[17];
    const float* cw1     = (const float*)d_in[18];
    const float* cb1     = (const float*)d_in[19];
    const float* cw2     = (const float*)d_in[20];
    const float* cb2     = (const float*)d_in[21];
    const float* cw3     = (const float*)d_in[22];
    const float* cb3     = (const float*)d_in[23];

    int N = in_sizes[0] / 3;
    int E = in_sizes[2];
    int NB = (N + 255) / 256;
    float invN = 1.f / (float)N;

    char* ws = (char*)d_ws;
    float* deg      = (float*)ws;                         ws += (size_t)N * 4;
    int*   cnt      = (int*)ws;                           ws += (size_t)N * 4;
    float* gsum     = (float*)ws;                         ws += HID * 4;
    float* A        = (float*)ws;                         ws += (size_t)N * HID * 4;
    float* P        = (float*)ws;                         ws += (size_t)N * HID * 4;
    float* ew       = (float*)ws;                         ws += (size_t)E * 4;
    int2*  csr      = (int2*)ws;                          ws += (size_t)E * 8;
    int*   row_ptr  = (int*)ws;                           ws += (size_t)(N + 1) * 4;
    int*   cursor   = (int*)ws;                           ws += (size_t)N * 4;
    int*   bsums    = (int*)ws;                           ws += 256 * 4;
    int*   bscan    = (int*)ws;                           ws += 256 * 4;
    float4* T3      = (float4*)ws;                        ws += (size_t)N * 16;
    float4* nf4     = (float4*)ws;                        ws += (size_t)N * 16;
    float* gbias    = (float*)ws;                         ws += HID * 4;
    ushort* w2h     = (ushort*)ws;                        ws += 65536 * 2;
    ushort* w2l     = (ushort*)ws;                        ws += 65536 * 2;
    ushort* a1h     = (ushort*)ws;                        ws += 65536 * 2;
    ushort* a1l     = (ushort*)ws;                        ws += 65536 * 2;

    float* out = (float*)d_out;  // [N] logits + [1] state value

    // --- zero deg+cnt+gsum in one memset
    hipMemsetAsync(deg, 0, (size_t)(2 * N + HID) * sizeof(float), stream);

    // --- weight prep for MFMA (one-time per launch; off critical path cost-wise)
    k_wprep<<<64, 256, 0, stream>>>(c2w, aw1, w2h, w2l, a1h, a1l);

    // --- edge MLP + degree + histogram
    k_edge<<<(E + 255) / 256, 256, 0, stream>>>(eid, epos, id_emb, pos_emb,
                                                ew_w1, ew_b1, ew_w2, ew_b2, ei, ew, deg, cnt, E);

    // --- parallel 3-phase scan (+ dinv + nf4 pack)
    k_scan_a<<<NB, 256, 0, stream>>>(cnt, row_ptr, bsums, deg, nf, nf4, N);
    k_scan_b<<<1, 256, 0, stream>>>(bsums, bscan, row_ptr, N, NB);
    k_scan_c<<<NB, 256, 0, stream>>>(row_ptr, cursor, bscan, N);

    // --- fill CSR
    k_fill<<<(E + 255) / 256, 256, 0, stream>>>(ei, ew, deg, cursor, csr, E);

    // --- layer 1 aggregate on raw features
    k_agg3<<<(N + 255) / 256, 256, 0, stream>>>(row_ptr, csr, nf4, deg, T3, N);

    // --- layer 2 aggregate with x1 recomputed on the fly
    k_gatherfused<<<(N + 3) / 4, 256, 0, stream>>>(row_ptr, csr, T3, deg, c1w, c1b, A, N);

    // --- MFMA fused conv2-GEMM + actor-GEMM (+ colsum); x2 stays on-chip
    k_gemm_mfma<<<(N + 31) / 32, 256, 0, stream>>>(A, c2b, w2h, w2l, a1h, a1l, P, gsum, N);

    // --- heads prep: gbias + critic value
    k_heads<<<2, 2 * HID, 0, stream>>>(gsum, aw1, ab1, gbias,
                                       cw1, cb1, cw2, cb2, cw3, cb3, out + N, invN);

    // --- logits epilogue
    k_logits<<<(N + 3) / 4, 256, 0, stream>>>(P, gbias, aw2, ab2, out, N);
}

// Round 13
// 509.489 us; speedup vs baseline: 3.7165x; 1.0399x over previous
//
#include <hip/hip_runtime.h>
#include <math.h>

#define HID 256

typedef __attribute__((ext_vector_type(8))) short short8;
typedef __attribute__((ext_vector_type(4))) float floatx4;

__device__ __forceinline__ ushort bf16_rne(float x) {
    uint u = __float_as_uint(x);
    uint r = (u + 0x7FFFu + ((u >> 16) & 1u)) >> 16;
    return (ushort)r;
}
__device__ __forceinline__ float bf16_to_f(ushort h) {
    return __uint_as_float(((uint)h) << 16);
}

// ---------- edge weight MLP (unchanged, proven)
__global__ void k_edge(const int* __restrict__ eid, const int* __restrict__ epos,
                       const float* __restrict__ id_emb, const float* __restrict__ pos_emb,
                       const float* __restrict__ w1, const float* __restrict__ b1,
                       const float* __restrict__ w2, const float* __restrict__ b2,
                       const int* __restrict__ ei, float* __restrict__ ew,
                       float* __restrict__ deg, int* __restrict__ cnt, int E) {
    __shared__ float sW1[100];
    __shared__ float sB1[10];
    __shared__ float sW2[10];
    __shared__ float sB2;
    int t = threadIdx.x;
    if (t < 100) sW1[t] = w1[t];
    if (t < 10) { sB1[t] = b1[t]; sW2[t] = w2[t]; }
    if (t == 0) sB2 = b2[0];
    __syncthreads();
    int e = blockIdx.x * blockDim.x + t;
    if (e >= E) return;
    int id = eid[e];
    int p  = epos[e];
    const float4* ide = (const float4*)(id_emb + (size_t)id * 8);
    float4 fa = ide[0], fb = ide[1];
    float f[10];
    f[0] = fa.x; f[1] = fa.y; f[2] = fa.z; f[3] = fa.w;
    f[4] = fb.x; f[5] = fb.y; f[6] = fb.z; f[7] = fb.w;
    f[8] = pos_emb[p * 2 + 0];
    f[9] = pos_emb[p * 2 + 1];
    float acc = sB2;
#pragma unroll
    for (int j = 0; j < 10; j++) {
        float h = sB1[j];
#pragma unroll
        for (int i = 0; i < 10; i++) h += f[i] * sW1[i * 10 + j];
        h = fmaxf(h, 0.f);
        acc += h * sW2[j];
    }
    float w = 1.f / (1.f + expf(-acc));
    ew[e] = w;
    int dst = ei[E + e];
    atomicAdd(&deg[dst], w);
    atomicAdd(&cnt[dst], 1);
}

// ---------- scan phase a (+dinv + nf4 pack + gsum zero + wprep in blocks 0..63)
// wprep: Frag[c][t][L][j] = W[32c + (L>>4)*8 + j][16t + (L&15)]
__global__ void k_scan_a(const int* __restrict__ cnt, int* __restrict__ row_ptr,
                         int* __restrict__ bsums,
                         float* __restrict__ deg, const float* __restrict__ nf,
                         float4* __restrict__ nf4, float* __restrict__ gsum,
                         const float* __restrict__ w2, const float* __restrict__ aw1,
                         ushort* __restrict__ w2h, ushort* __restrict__ w2l,
                         ushort* __restrict__ a1h, ushort* __restrict__ a1l, int N) {
    __shared__ int s[256];
    int b = blockIdx.x, t = threadIdx.x;
    int i = b * 256 + t;
    if (b == 0) gsum[t] = 0.f;
    if (b < 64) {  // wprep: 16384 fragment groups
        int gid = b * 256 + t;
        int mat = gid >> 13;
        int rem = gid & 8191;
        int c = rem >> 10;
        int tt = (rem >> 6) & 15;
        int L = rem & 63;
        int k0 = 32 * c + (L >> 4) * 8;
        int n  = 16 * tt + (L & 15);
        const float* W = mat ? aw1 : w2;
        ushort* H  = mat ? a1h : w2h;
        ushort* Lo = mat ? a1l : w2l;
        short8 hv, lv;
#pragma unroll
        for (int j = 0; j < 8; j++) {
            float x = W[(size_t)(k0 + j) * HID + n];
            ushort h = bf16_rne(x);
            hv[j] = (short)h;
            lv[j] = (short)bf16_rne(x - bf16_to_f(h));
        }
        size_t off = (size_t)rem * 8;
        *(short8*)(H + off) = hv;
        *(short8*)(Lo + off) = lv;
    }
    if (i < N) {
        deg[i] = 1.f / sqrtf(deg[i] + 1.f);
        nf4[i] = make_float4(nf[i * 3 + 0], nf[i * 3 + 1], nf[i * 3 + 2], 0.f);
    }
    int v = (i < N) ? cnt[i] : 0;
    s[t] = v;
    __syncthreads();
    for (int off = 1; off < 256; off <<= 1) {
        int u = (t >= off) ? s[t - off] : 0;
        __syncthreads();
        s[t] += u;
        __syncthreads();
    }
    int incl = s[t];
    if (i < N) row_ptr[i] = incl - v;
    if (t == 255) bsums[b] = incl;
}

// ---------- scan phase c (absorbs old phase b): per-block offset from bsums prefix
__global__ void k_scan_c(int* __restrict__ row_ptr, int* __restrict__ cursor,
                         const int* __restrict__ bsums, int N, int NB) {
    __shared__ int s[256];
    int b = blockIdx.x, t = threadIdx.x;
    int v = (t < NB) ? bsums[t] : 0;
    s[t] = (t < b) ? v : 0;            // only blocks before mine
    int tot = v;                        // for grand total (last block only)
    __syncthreads();
    for (int off = 128; off > 0; off >>= 1) {
        if (t < off) s[t] += s[t + off];
        __syncthreads();
    }
    int boff = s[0];
    int i = b * 256 + t;
    if (i < N) {
        int rp = row_ptr[i] + boff;
        row_ptr[i] = rp;
        cursor[i] = rp;
    }
    // grand total: last block recomputes full sum
    if (b == NB - 1) {
        __syncthreads();
        s[t] = (t < NB) ? bsums[t] : 0;
        __syncthreads();
        for (int off = 128; off > 0; off >>= 1) {
            if (t < off) s[t] += s[t + off];
            __syncthreads();
        }
        if (t == 0) row_ptr[N] = s[0];
    }
    (void)tot;
}

// ---------- fill CSR
__global__ void k_fill(const int* __restrict__ ei, const float* __restrict__ ew,
                       const float* __restrict__ dinv, int* __restrict__ cursor,
                       int2* __restrict__ csr, int E) {
    int e = blockIdx.x * blockDim.x + threadIdx.x;
    if (e >= E) return;
    int src = ei[e];
    int dst = ei[E + e];
    int slot = atomicAdd(&cursor[dst], 1);
    float norm = dinv[src] * ew[e] * dinv[dst];
    csr[slot] = make_int2(src, __float_as_int(norm));
}

// ---------- layer-1 aggregation on raw packed features
__global__ void k_agg3(const int* __restrict__ row_ptr, const int2* __restrict__ csr,
                       const float4* __restrict__ nf4, const float* __restrict__ dinv,
                       float4* __restrict__ T3, int N) {
    int n = blockIdx.x * blockDim.x + threadIdx.x;
    if (n >= N) return;
    int s = row_ptr[n];
    int e = row_ptr[n + 1];
    float ax = 0.f, ay = 0.f, az = 0.f;
    for (int i = s; i < e; i++) {
        int2 sn = csr[i];
        float w = __int_as_float(sn.y);
        float4 v = nf4[sn.x];
        ax = fmaf(w, v.x, ax);
        ay = fmaf(w, v.y, ay);
        az = fmaf(w, v.z, az);
    }
    float d = dinv[n];
    float dd = d * d;
    float4 v = nf4[n];
    ax = fmaf(dd, v.x, ax);
    ay = fmaf(dd, v.y, ay);
    az = fmaf(dd, v.z, az);
    T3[n] = make_float4(ax, ay, az, 0.f);
}

// ---------- fused layer-2 aggregation; epilogue writes A as bf16 hi/lo pair
__global__ void k_gatherfused(const int* __restrict__ row_ptr, const int2* __restrict__ csr,
                              const float4* __restrict__ T3, const float* __restrict__ dinv,
                              const float* __restrict__ cw, const float* __restrict__ cb,
                              ushort* __restrict__ Ah, ushort* __restrict__ Al, int N) {
    int lane = threadIdx.x & 63;
    int wv = threadIdx.x >> 6;
    int n = blockIdx.x * 4 + wv;
    if (n >= N) return;
    const float4 w0 = *(const float4*)(cw + 4 * lane);
    const float4 w1 = *(const float4*)(cw + HID + 4 * lane);
    const float4 w2 = *(const float4*)(cw + 2 * HID + 4 * lane);
    const float4 bv = *(const float4*)(cb + 4 * lane);
    int s = row_ptr[n];
    int e = row_ptr[n + 1];
    float4 acc = make_float4(0.f, 0.f, 0.f, 0.f);
    for (int i = s; i < e; i++) {
        int2 sn = csr[i];
        float w = __int_as_float(sn.y);
        float4 t = T3[sn.x];
        float xx = fmaxf(fmaf(t.x, w0.x, fmaf(t.y, w1.x, fmaf(t.z, w2.x, bv.x))), 0.f);
        float xy = fmaxf(fmaf(t.x, w0.y, fmaf(t.y, w1.y, fmaf(t.z, w2.y, bv.y))), 0.f);
        float xz = fmaxf(fmaf(t.x, w0.z, fmaf(t.y, w1.z, fmaf(t.z, w2.z, bv.z))), 0.f);
        float xw = fmaxf(fmaf(t.x, w0.w, fmaf(t.y, w1.w, fmaf(t.z, w2.w, bv.w))), 0.f);
        acc.x = fmaf(w, xx, acc.x);
        acc.y = fmaf(w, xy, acc.y);
        acc.z = fmaf(w, xz, acc.z);
        acc.w = fmaf(w, xw, acc.w);
    }
    float d = dinv[n];
    float dd = d * d;
    float4 t = T3[n];
    float xx = fmaxf(fmaf(t.x, w0.x, fmaf(t.y, w1.x, fmaf(t.z, w2.x, bv.x))), 0.f);
    float xy = fmaxf(fmaf(t.x, w0.y, fmaf(t.y, w1.y, fmaf(t.z, w2.y, bv.y))), 0.f);
    float xz = fmaxf(fmaf(t.x, w0.z, fmaf(t.y, w1.z, fmaf(t.z, w2.z, bv.z))), 0.f);
    float xw = fmaxf(fmaf(t.x, w0.w, fmaf(t.y, w1.w, fmaf(t.z, w2.w, bv.w))), 0.f);
    acc.x = fmaf(dd, xx, acc.x);
    acc.y = fmaf(dd, xy, acc.y);
    acc.z = fmaf(dd, xz, acc.z);
    acc.w = fmaf(dd, xw, acc.w);
    // split to bf16 hi/lo and store
    ushort4 hv, lv;
    ushort h;
    h = bf16_rne(acc.x); hv.x = h; lv.x = bf16_rne(acc.x - bf16_to_f(h));
    h = bf16_rne(acc.y); hv.y = h; lv.y = bf16_rne(acc.y - bf16_to_f(h));
    h = bf16_rne(acc.z); hv.z = h; lv.z = bf16_rne(acc.z - bf16_to_f(h));
    h = bf16_rne(acc.w); hv.w = h; lv.w = bf16_rne(acc.w - bf16_to_f(h));
    size_t base = (size_t)n * HID + lane * 4;
    *(ushort4*)(Ah + base) = hv;
    *(ushort4*)(Al + base) = lv;
}

// ================= MFMA double GEMM (bf16x2 split, 3 products):
// phase 1: x2 = relu(A @ W2 + b2), A fragments loaded DIRECT from global bf16 hi/lo
// epilogue: colsum -> gsum; x2 split to bf16 LDS
// phase 2: P = x2 @ aw1_top
// 32-row tile/block, 4 waves: wave w -> m-tile (w&1), n-tiles (w>>1)*8..+7
#define ASTRIDE 264

__global__ __launch_bounds__(256, 4) void k_gemm_mfma(
        const ushort* __restrict__ Ah, const ushort* __restrict__ Al,
        const float* __restrict__ b2,
        const ushort* __restrict__ w2h, const ushort* __restrict__ w2l,
        const ushort* __restrict__ a1h, const ushort* __restrict__ a1l,
        float* __restrict__ P, float* __restrict__ gsum, int N) {
    __shared__ ushort Hs[32 * ASTRIDE];
    __shared__ ushort Ls[32 * ASTRIDE];
    int tid = threadIdx.x;
    int n0 = blockIdx.x * 32;

    int w = tid >> 6;
    int L = tid & 63;
    int mt = w & 1;
    int tb = (w >> 1) * 8;
    int quad = L >> 4, ln = L & 15;
    int arow = mt * 16 + ln;
    int grow = n0 + arow;
    if (grow >= N) grow = N - 1;   // clamp; results for tail rows are discarded

    // --- phase 1: x2 = relu(A @ W2 + b2), A fragments direct from global
    floatx4 acc[8];
#pragma unroll
    for (int i = 0; i < 8; i++) acc[i] = 0.f;
    for (int c = 0; c < 8; c++) {
        size_t abase = (size_t)grow * HID + 32 * c + quad * 8;
        short8 ah = *(const short8*)(Ah + abase);
        short8 al = *(const short8*)(Al + abase);
#pragma unroll
        for (int tt = 0; tt < 8; tt++) {
            size_t off = ((size_t)(c * 16 + tb + tt) * 64 + L) * 8;
            short8 bh = *(const short8*)(w2h + off);
            short8 bl = *(const short8*)(w2l + off);
            acc[tt] = __builtin_amdgcn_mfma_f32_16x16x32_bf16(ah, bh, acc[tt], 0, 0, 0);
            acc[tt] = __builtin_amdgcn_mfma_f32_16x16x32_bf16(ah, bl, acc[tt], 0, 0, 0);
            acc[tt] = __builtin_amdgcn_mfma_f32_16x16x32_bf16(al, bh, acc[tt], 0, 0, 0);
        }
    }

    // --- epilogue 1: bias + relu + colsum (C layout: col=ln, row=quad*4+reg)
#pragma unroll
    for (int tt = 0; tt < 8; tt++) {
        int col = (tb + tt) * 16 + ln;
        float bb = b2[col];
        float s = 0.f;
#pragma unroll
        for (int r = 0; r < 4; r++) {
            int row = n0 + mt * 16 + quad * 4 + r;
            float v = fmaxf(acc[tt][r] + bb, 0.f);
            acc[tt][r] = v;
            if (row < N) s += v;
        }
        s += __shfl_down(s, 32, 64);
        s += __shfl_down(s, 16, 64);
        if (L < 16) atomicAdd(&gsum[col], s);
    }

    // --- split x2 to bf16 hi/lo in LDS
#pragma unroll
    for (int tt = 0; tt < 8; tt++) {
        int col = (tb + tt) * 16 + ln;
#pragma unroll
        for (int r = 0; r < 4; r++) {
            int row = mt * 16 + quad * 4 + r;
            float v = acc[tt][r];
            ushort h = bf16_rne(v);
            Hs[row * ASTRIDE + col] = h;
            Ls[row * ASTRIDE + col] = bf16_rne(v - bf16_to_f(h));
        }
    }
    __syncthreads();

    // --- phase 2: P = x2 @ aw1_top
    floatx4 acc2[8];
#pragma unroll
    for (int i = 0; i < 8; i++) acc2[i] = 0.f;
    for (int c = 0; c < 8; c++) {
        short8 ah = *(const short8*)&Hs[arow * ASTRIDE + 32 * c + quad * 8];
        short8 al = *(const short8*)&Ls[arow * ASTRIDE + 32 * c + quad * 8];
#pragma unroll
        for (int tt = 0; tt < 8; tt++) {
            size_t off = ((size_t)(c * 16 + tb + tt) * 64 + L) * 8;
            short8 bh = *(const short8*)(a1h + off);
            short8 bl = *(const short8*)(a1l + off);
            acc2[tt] = __builtin_amdgcn_mfma_f32_16x16x32_bf16(ah, bh, acc2[tt], 0, 0, 0);
            acc2[tt] = __builtin_amdgcn_mfma_f32_16x16x32_bf16(ah, bl, acc2[tt], 0, 0, 0);
            acc2[tt] = __builtin_amdgcn_mfma_f32_16x16x32_bf16(al, bh, acc2[tt], 0, 0, 0);
        }
    }

    // --- store P (C layout)
#pragma unroll
    for (int tt = 0; tt < 8; tt++) {
        int col = (tb + tt) * 16 + ln;
#pragma unroll
        for (int r = 0; r < 4; r++) {
            int row = n0 + mt * 16 + quad * 4 + r;
            if (row < N) P[(size_t)row * HID + col] = acc2[tt][r];
        }
    }
}

// ---------- logits epilogue
__global__ void k_logits(const float* __restrict__ P, const float* __restrict__ gbias,
                         const float* __restrict__ aw2, const float* __restrict__ ab2,
                         float* __restrict__ out, int N) {
    int lane = threadIdx.x & 63;
    int wv = threadIdx.x >> 6;
    int n = blockIdx.x * 4 + wv;
    if (n >= N) return;
    float4 p = *(const float4*)(P + (size_t)n * HID + 4 * lane);
    float4 gb = *(const float4*)(gbias + 4 * lane);
    float4 w2 = *(const float4*)(aw2 + 4 * lane);
    float v = fmaxf(p.x + gb.x, 0.f) * w2.x
            + fmaxf(p.y + gb.y, 0.f) * w2.y
            + fmaxf(p.z + gb.z, 0.f) * w2.z
            + fmaxf(p.w + gb.w, 0.f) * w2.w;
#pragma unroll
    for (int off = 32; off > 0; off >>= 1) v += __shfl_down(v, off, 64);
    if (lane == 0) out[n] = v + ab2[0];
}

// ---------- merged head prep
__global__ void k_heads(const float* __restrict__ gsum,
                        const float* __restrict__ aw1, const float* __restrict__ ab1,
                        float* __restrict__ gbias,
                        const float* __restrict__ cw1, const float* __restrict__ cb1,
                        const float* __restrict__ cw2, const float* __restrict__ cb2,
                        const float* __restrict__ cw3, const float* __restrict__ cb3,
                        float* __restrict__ sv_out, float invN) {
    int t = threadIdx.x;  // 512
    if (blockIdx.x == 0) {
        if (t < HID) {
            float s = ab1[t];
            for (int j = 0; j < HID; j++) s += gsum[j] * invN * aw1[(HID + j) * HID + t];
            gbias[t] = s;
        }
        return;
    }
    __shared__ float p[2 * HID];
    __shared__ float c1[2 * HID];
    __shared__ float c2[HID];
    p[t] = gsum[t & (HID - 1)] * invN;
    __syncthreads();
    float s = cb1[t];
    for (int i = 0; i < 2 * HID; i++) s += p[i] * cw1[i * 2 * HID + t];
    c1[t] = fmaxf(s, 0.f);
    __syncthreads();
    if (t < HID) {
        float s2 = cb2[t];
        for (int i = 0; i < 2 * HID; i++) s2 += c1[i] * cw2[i * HID + t];
        c2[t] = fmaxf(s2, 0.f) * cw3[t];
    }
    __syncthreads();
    for (int st = HID / 2; st > 0; st >>= 1) {
        if (t < st) c2[t] += c2[t + st];
        __syncthreads();
    }
    if (t == 0) sv_out[0] = c2[0] + cb3[0];
}

extern "C" void kernel_launch(void* const* d_in, const int* in_sizes, int n_in,
                              void* d_out, int out_size, void* d_ws, size_t ws_size,
                              hipStream_t stream) {
    const float* nf      = (const float*)d_in[0];
    const int*   ei      = (const int*)d_in[1];
    const int*   eid     = (const int*)d_in[2];
    const int*   epos    = (const int*)d_in[3];
    const float* id_emb  = (const float*)d_in[4];
    const float* pos_emb = (const float*)d_in[5];
    const float* ew_w1   = (const float*)d_in[6];
    const float* ew_b1   = (const float*)d_in[7];
    const float* ew_w2   = (const float*)d_in[8];
    const float* ew_b2   = (const float*)d_in[9];
    const float* c1w     = (const float*)d_in[10];
    const float* c1b     = (const float*)d_in[11];
    const float* c2w     = (const float*)d_in[12];
    const float* c2b     = (const float*)d_in[13];
    const float* aw1     = (const float*)d_in[14];
    const float* ab1     = (const float*)d_in[15];
    const float* aw2     = (const float*)d_in[16];
    const float* ab2     = (const float*)d_in[17];
    const float* cw1     = (const float*)d_in[18];
    const float* cb1     = (const float*)d_in[19];
    const float* cw2     = (const float*)d_in[20];
    const float* cb2     = (const float*)d_in[21];
    const float* cw3     = (const float*)d_in[22];
    const float* cb3     = (const float*)d_in[23];

    int N = in_sizes[0] / 3;
    int E = in_sizes[2];
    int NB = (N + 255) / 256;
    float invN = 1.f / (float)N;

    char* ws = (char*)d_ws;
    float* deg      = (float*)ws;                         ws += (size_t)N * 4;
    int*   cnt      = (int*)ws;                           ws += (size_t)N * 4;
    float* gsum     = (float*)ws;                         ws += HID * 4;
    ushort* Ah      = (ushort*)ws;                        ws += (size_t)N * HID * 2;
    ushort* Al      = (ushort*)ws;                        ws += (size_t)N * HID * 2;
    float* P        = (float*)ws;                         ws += (size_t)N * HID * 4;
    float* ew       = (float*)ws;                         ws += (size_t)E * 4;
    int2*  csr      = (int2*)ws;                          ws += (size_t)E * 8;
    int*   row_ptr  = (int*)ws;                           ws += (size_t)(N + 1) * 4;
    int*   cursor   = (int*)ws;                           ws += (size_t)N * 4;
    int*   bsums    = (int*)ws;                           ws += 256 * 4;
    float4* T3      = (float4*)ws;                        ws += (size_t)N * 16;
    float4* nf4     = (float4*)ws;                        ws += (size_t)N * 16;
    float* gbias    = (float*)ws;                         ws += HID * 4;
    ushort* w2h     = (ushort*)ws;                        ws += 65536 * 2;
    ushort* w2l     = (ushort*)ws;                        ws += 65536 * 2;
    ushort* a1h     = (ushort*)ws;                        ws += 65536 * 2;
    ushort* a1l     = (ushort*)ws;                        ws += 65536 * 2;

    float* out = (float*)d_out;  // [N] logits + [1] state value

    // --- zero deg+cnt in one memset (gsum zeroed in k_scan_a)
    hipMemsetAsync(deg, 0, (size_t)(2 * N) * sizeof(float), stream);

    // --- edge MLP + degree + histogram
    k_edge<<<(E + 255) / 256, 256, 0, stream>>>(eid, epos, id_emb, pos_emb,
                                                ew_w1, ew_b1, ew_w2, ew_b2, ei, ew, deg, cnt, E);

    // --- scan a (+ dinv + nf4 pack + gsum zero + wprep), then c (absorbs b)
    k_scan_a<<<NB, 256, 0, stream>>>(cnt, row_ptr, bsums, deg, nf, nf4, gsum,
                                     c2w, aw1, w2h, w2l, a1h, a1l, N);
    k_scan_c<<<NB, 256, 0, stream>>>(row_ptr, cursor, bsums, N, NB);

    // --- fill CSR
    k_fill<<<(E + 255) / 256, 256, 0, stream>>>(ei, ew, deg, cursor, csr, E);

    // --- layer 1 aggregate on raw features
    k_agg3<<<(N + 255) / 256, 256, 0, stream>>>(row_ptr, csr, nf4, deg, T3, N);

    // --- layer 2 aggregate; writes A as bf16 hi/lo
    k_gatherfused<<<(N + 3) / 4, 256, 0, stream>>>(row_ptr, csr, T3, deg, c1w, c1b, Ah, Al, N);

    // --- MFMA fused conv2-GEMM + actor-GEMM (+ colsum); x2 stays on-chip
    k_gemm_mfma<<<(N + 31) / 32, 256, 0, stream>>>(Ah, Al, c2b, w2h, w2l, a1h, a1l, P, gsum, N);

    // --- heads prep: gbias + critic value
    k_heads<<<2, 2 * HID, 0, stream>>>(gsum, aw1, ab1, gbias,
                                       cw1, cb1, cw2, cb2, cw3, cb3, out + N, invN);

    // --- logits epilogue
    k_logits<<<(N + 3) / 4, 256, 0, stream>>>(P, gbias, aw2, ab2, out, N);
}

// Round 14
// 448.656 us; speedup vs baseline: 4.2204x; 1.1356x over previous
//
#include <hip/hip_runtime.h>
#include <math.h>

#define HID 256

typedef __attribute__((ext_vector_type(8))) short short8;
typedef __attribute__((ext_vector_type(4))) float floatx4;

__device__ __forceinline__ ushort bf16_rne(float x) {
    uint u = __float_as_uint(x);
    uint r = (u + 0x7FFFu + ((u >> 16) & 1u)) >> 16;
    return (ushort)r;
}
__device__ __forceinline__ float bf16_to_f(ushort h) {
    return __uint_as_float(((uint)h) << 16);
}

// ---------- edge weight MLP (unchanged, proven)
__global__ void k_edge(const int* __restrict__ eid, const int* __restrict__ epos,
                       const float* __restrict__ id_emb, const float* __restrict__ pos_emb,
                       const float* __restrict__ w1, const float* __restrict__ b1,
                       const float* __restrict__ w2, const float* __restrict__ b2,
                       const int* __restrict__ ei, float* __restrict__ ew,
                       float* __restrict__ deg, int* __restrict__ cnt, int E) {
    __shared__ float sW1[100];
    __shared__ float sB1[10];
    __shared__ float sW2[10];
    __shared__ float sB2;
    int t = threadIdx.x;
    if (t < 100) sW1[t] = w1[t];
    if (t < 10) { sB1[t] = b1[t]; sW2[t] = w2[t]; }
    if (t == 0) sB2 = b2[0];
    __syncthreads();
    int e = blockIdx.x * blockDim.x + t;
    if (e >= E) return;
    int id = eid[e];
    int p  = epos[e];
    const float4* ide = (const float4*)(id_emb + (size_t)id * 8);
    float4 fa = ide[0], fb = ide[1];
    float f[10];
    f[0] = fa.x; f[1] = fa.y; f[2] = fa.z; f[3] = fa.w;
    f[4] = fb.x; f[5] = fb.y; f[6] = fb.z; f[7] = fb.w;
    f[8] = pos_emb[p * 2 + 0];
    f[9] = pos_emb[p * 2 + 1];
    float acc = sB2;
#pragma unroll
    for (int j = 0; j < 10; j++) {
        float h = sB1[j];
#pragma unroll
        for (int i = 0; i < 10; i++) h += f[i] * sW1[i * 10 + j];
        h = fmaxf(h, 0.f);
        acc += h * sW2[j];
    }
    float w = 1.f / (1.f + expf(-acc));
    ew[e] = w;
    int dst = ei[E + e];
    atomicAdd(&deg[dst], w);
    atomicAdd(&cnt[dst], 1);
}

// ---------- scan phase a (+dinv + nf4 pack + gsum zero + wprep in blocks 0..63)
// wprep: Frag[c][t][L][j] = W[32c + (L>>4)*8 + j][16t + (L&15)]
__global__ void k_scan_a(const int* __restrict__ cnt, int* __restrict__ row_ptr,
                         int* __restrict__ bsums,
                         float* __restrict__ deg, const float* __restrict__ nf,
                         float4* __restrict__ nf4, float* __restrict__ gsum,
                         const float* __restrict__ w2, const float* __restrict__ aw1,
                         ushort* __restrict__ w2h, ushort* __restrict__ w2l,
                         ushort* __restrict__ a1h, ushort* __restrict__ a1l, int N) {
    __shared__ int s[256];
    int b = blockIdx.x, t = threadIdx.x;
    int i = b * 256 + t;
    if (b == 0) gsum[t] = 0.f;
    if (b < 64) {  // wprep: 16384 fragment groups
        int gid = b * 256 + t;
        int mat = gid >> 13;
        int rem = gid & 8191;
        int c = rem >> 10;
        int tt = (rem >> 6) & 15;
        int L = rem & 63;
        int k0 = 32 * c + (L >> 4) * 8;
        int n  = 16 * tt + (L & 15);
        const float* W = mat ? aw1 : w2;
        ushort* H  = mat ? a1h : w2h;
        ushort* Lo = mat ? a1l : w2l;
        short8 hv, lv;
#pragma unroll
        for (int j = 0; j < 8; j++) {
            float x = W[(size_t)(k0 + j) * HID + n];
            ushort h = bf16_rne(x);
            hv[j] = (short)h;
            lv[j] = (short)bf16_rne(x - bf16_to_f(h));
        }
        size_t off = (size_t)rem * 8;
        *(short8*)(H + off) = hv;
        *(short8*)(Lo + off) = lv;
    }
    if (i < N) {
        deg[i] = 1.f / sqrtf(deg[i] + 1.f);
        nf4[i] = make_float4(nf[i * 3 + 0], nf[i * 3 + 1], nf[i * 3 + 2], 0.f);
    }
    int v = (i < N) ? cnt[i] : 0;
    s[t] = v;
    __syncthreads();
    for (int off = 1; off < 256; off <<= 1) {
        int u = (t >= off) ? s[t - off] : 0;
        __syncthreads();
        s[t] += u;
        __syncthreads();
    }
    int incl = s[t];
    if (i < N) row_ptr[i] = incl - v;
    if (t == 255) bsums[b] = incl;
}

// ---------- scan phase c (absorbs old phase b): per-block offset from bsums prefix
__global__ void k_scan_c(int* __restrict__ row_ptr, int* __restrict__ cursor,
                         const int* __restrict__ bsums, int N, int NB) {
    __shared__ int s[256];
    int b = blockIdx.x, t = threadIdx.x;
    int v = (t < NB) ? bsums[t] : 0;
    s[t] = (t < b) ? v : 0;
    __syncthreads();
    for (int off = 128; off > 0; off >>= 1) {
        if (t < off) s[t] += s[t + off];
        __syncthreads();
    }
    int boff = s[0];
    int i = b * 256 + t;
    if (i < N) {
        int rp = row_ptr[i] + boff;
        row_ptr[i] = rp;
        cursor[i] = rp;
    }
    if (b == NB - 1) {
        __syncthreads();
        s[t] = (t < NB) ? bsums[t] : 0;
        __syncthreads();
        for (int off = 128; off > 0; off >>= 1) {
            if (t < off) s[t] += s[t + off];
            __syncthreads();
        }
        if (t == 0) row_ptr[N] = s[0];
    }
}

// ---------- fill CSR
__global__ void k_fill(const int* __restrict__ ei, const float* __restrict__ ew,
                       const float* __restrict__ dinv, int* __restrict__ cursor,
                       int2* __restrict__ csr, int E) {
    int e = blockIdx.x * blockDim.x + threadIdx.x;
    if (e >= E) return;
    int src = ei[e];
    int dst = ei[E + e];
    int slot = atomicAdd(&cursor[dst], 1);
    float norm = dinv[src] * ew[e] * dinv[dst];
    csr[slot] = make_int2(src, __float_as_int(norm));
}

// ---------- layer-1 aggregation on raw packed features
__global__ void k_agg3(const int* __restrict__ row_ptr, const int2* __restrict__ csr,
                       const float4* __restrict__ nf4, const float* __restrict__ dinv,
                       float4* __restrict__ T3, int N) {
    int n = blockIdx.x * blockDim.x + threadIdx.x;
    if (n >= N) return;
    int s = row_ptr[n];
    int e = row_ptr[n + 1];
    float ax = 0.f, ay = 0.f, az = 0.f;
    for (int i = s; i < e; i++) {
        int2 sn = csr[i];
        float w = __int_as_float(sn.y);
        float4 v = nf4[sn.x];
        ax = fmaf(w, v.x, ax);
        ay = fmaf(w, v.y, ay);
        az = fmaf(w, v.z, az);
    }
    float d = dinv[n];
    float dd = d * d;
    float4 v = nf4[n];
    ax = fmaf(dd, v.x, ax);
    ay = fmaf(dd, v.y, ay);
    az = fmaf(dd, v.z, az);
    T3[n] = make_float4(ax, ay, az, 0.f);
}

// ---------- fused layer-2 aggregation; epilogue writes A as bf16 hi/lo pair
__global__ void k_gatherfused(const int* __restrict__ row_ptr, const int2* __restrict__ csr,
                              const float4* __restrict__ T3, const float* __restrict__ dinv,
                              const float* __restrict__ cw, const float* __restrict__ cb,
                              ushort* __restrict__ Ah, ushort* __restrict__ Al, int N) {
    int lane = threadIdx.x & 63;
    int wv = threadIdx.x >> 6;
    int n = blockIdx.x * 4 + wv;
    if (n >= N) return;
    const float4 w0 = *(const float4*)(cw + 4 * lane);
    const float4 w1 = *(const float4*)(cw + HID + 4 * lane);
    const float4 w2 = *(const float4*)(cw + 2 * HID + 4 * lane);
    const float4 bv = *(const float4*)(cb + 4 * lane);
    int s = row_ptr[n];
    int e = row_ptr[n + 1];
    float4 acc = make_float4(0.f, 0.f, 0.f, 0.f);
    for (int i = s; i < e; i++) {
        int2 sn = csr[i];
        float w = __int_as_float(sn.y);
        float4 t = T3[sn.x];
        float xx = fmaxf(fmaf(t.x, w0.x, fmaf(t.y, w1.x, fmaf(t.z, w2.x, bv.x))), 0.f);
        float xy = fmaxf(fmaf(t.x, w0.y, fmaf(t.y, w1.y, fmaf(t.z, w2.y, bv.y))), 0.f);
        float xz = fmaxf(fmaf(t.x, w0.z, fmaf(t.y, w1.z, fmaf(t.z, w2.z, bv.z))), 0.f);
        float xw = fmaxf(fmaf(t.x, w0.w, fmaf(t.y, w1.w, fmaf(t.z, w2.w, bv.w))), 0.f);
        acc.x = fmaf(w, xx, acc.x);
        acc.y = fmaf(w, xy, acc.y);
        acc.z = fmaf(w, xz, acc.z);
        acc.w = fmaf(w, xw, acc.w);
    }
    float d = dinv[n];
    float dd = d * d;
    float4 t = T3[n];
    float xx = fmaxf(fmaf(t.x, w0.x, fmaf(t.y, w1.x, fmaf(t.z, w2.x, bv.x))), 0.f);
    float xy = fmaxf(fmaf(t.x, w0.y, fmaf(t.y, w1.y, fmaf(t.z, w2.y, bv.y))), 0.f);
    float xz = fmaxf(fmaf(t.x, w0.z, fmaf(t.y, w1.z, fmaf(t.z, w2.z, bv.z))), 0.f);
    float xw = fmaxf(fmaf(t.x, w0.w, fmaf(t.y, w1.w, fmaf(t.z, w2.w, bv.w))), 0.f);
    acc.x = fmaf(dd, xx, acc.x);
    acc.y = fmaf(dd, xy, acc.y);
    acc.z = fmaf(dd, xz, acc.z);
    acc.w = fmaf(dd, xw, acc.w);
    ushort4 hv, lv;
    ushort h;
    h = bf16_rne(acc.x); hv.x = h; lv.x = bf16_rne(acc.x - bf16_to_f(h));
    h = bf16_rne(acc.y); hv.y = h; lv.y = bf16_rne(acc.y - bf16_to_f(h));
    h = bf16_rne(acc.z); hv.z = h; lv.z = bf16_rne(acc.z - bf16_to_f(h));
    h = bf16_rne(acc.w); hv.w = h; lv.w = bf16_rne(acc.w - bf16_to_f(h));
    size_t base = (size_t)n * HID + lane * 4;
    *(ushort4*)(Ah + base) = hv;
    *(ushort4*)(Al + base) = lv;
}

// ================= MFMA double GEMM, 64-row tile, 4 n-tiles x 4 m-subtiles per wave:
// phase 1: x2 = relu(A @ W2 + b2), A direct from global bf16 hi/lo
// epilogue: colsum -> gsum; x2 split to bf16 LDS
// phase 2: P = x2 @ aw1_top
// wave w owns n-tiles 4w..4w+3 (cols 64w..64w+63), all 4 m-subtiles (rows n0..n0+63)
#define ASTRIDE 264

__global__ __launch_bounds__(256, 2) void k_gemm_mfma(
        const ushort* __restrict__ Ah, const ushort* __restrict__ Al,
        const float* __restrict__ b2,
        const ushort* __restrict__ w2h, const ushort* __restrict__ w2l,
        const ushort* __restrict__ a1h, const ushort* __restrict__ a1l,
        float* __restrict__ P, float* __restrict__ gsum, int N) {
    __shared__ ushort Hs[64 * ASTRIDE];
    __shared__ ushort Ls[64 * ASTRIDE];
    int tid = threadIdx.x;
    int n0 = blockIdx.x * 64;
    int w = tid >> 6;
    int L = tid & 63;
    int quad = L >> 4, ln = L & 15;

    int arow[4];
#pragma unroll
    for (int mt = 0; mt < 4; mt++) {
        int r = n0 + mt * 16 + ln;
        arow[mt] = (r < N) ? r : (N - 1);   // clamp; tail results discarded
    }

    // --- phase 1
    floatx4 acc[4][4];  // [nt][mt]
#pragma unroll
    for (int i = 0; i < 4; i++)
#pragma unroll
        for (int j = 0; j < 4; j++) acc[i][j] = 0.f;

    for (int c = 0; c < 8; c++) {
        short8 ahf[4], alf[4];
#pragma unroll
        for (int mt = 0; mt < 4; mt++) {
            size_t ab = (size_t)arow[mt] * HID + 32 * c + quad * 8;
            ahf[mt] = *(const short8*)(Ah + ab);
            alf[mt] = *(const short8*)(Al + ab);
        }
#pragma unroll
        for (int nt = 0; nt < 4; nt++) {
            int t = 4 * w + nt;
            size_t off = ((size_t)(c * 16 + t) * 64 + L) * 8;
            short8 bh = *(const short8*)(w2h + off);
            short8 bl = *(const short8*)(w2l + off);
#pragma unroll
            for (int mt = 0; mt < 4; mt++) {
                acc[nt][mt] = __builtin_amdgcn_mfma_f32_16x16x32_bf16(ahf[mt], bh, acc[nt][mt], 0, 0, 0);
                acc[nt][mt] = __builtin_amdgcn_mfma_f32_16x16x32_bf16(ahf[mt], bl, acc[nt][mt], 0, 0, 0);
                acc[nt][mt] = __builtin_amdgcn_mfma_f32_16x16x32_bf16(alf[mt], bh, acc[nt][mt], 0, 0, 0);
            }
        }
    }

    // --- epilogue 1: bias + relu + colsum (C layout: col=ln, row=quad*4+reg)
#pragma unroll
    for (int nt = 0; nt < 4; nt++) {
        int col = (4 * w + nt) * 16 + ln;
        float bb = b2[col];
        float s = 0.f;
#pragma unroll
        for (int mt = 0; mt < 4; mt++) {
#pragma unroll
            for (int r = 0; r < 4; r++) {
                int row = n0 + mt * 16 + quad * 4 + r;
                float v = fmaxf(acc[nt][mt][r] + bb, 0.f);
                acc[nt][mt][r] = v;
                if (row < N) s += v;
            }
        }
        s += __shfl_down(s, 32, 64);
        s += __shfl_down(s, 16, 64);
        if (L < 16) atomicAdd(&gsum[col], s);
    }

    // --- split x2 to bf16 hi/lo in LDS
#pragma unroll
    for (int nt = 0; nt < 4; nt++) {
        int col = (4 * w + nt) * 16 + ln;
#pragma unroll
        for (int mt = 0; mt < 4; mt++) {
#pragma unroll
            for (int r = 0; r < 4; r++) {
                int row = mt * 16 + quad * 4 + r;
                float v = acc[nt][mt][r];
                ushort h = bf16_rne(v);
                Hs[row * ASTRIDE + col] = h;
                Ls[row * ASTRIDE + col] = bf16_rne(v - bf16_to_f(h));
            }
        }
    }
    __syncthreads();

    // --- phase 2: P = x2 @ aw1_top
    floatx4 acc2[4][4];
#pragma unroll
    for (int i = 0; i < 4; i++)
#pragma unroll
        for (int j = 0; j < 4; j++) acc2[i][j] = 0.f;

    for (int c = 0; c < 8; c++) {
        short8 ahf[4], alf[4];
#pragma unroll
        for (int mt = 0; mt < 4; mt++) {
            int base = (mt * 16 + ln) * ASTRIDE + 32 * c + quad * 8;
            ahf[mt] = *(const short8*)&Hs[base];
            alf[mt] = *(const short8*)&Ls[base];
        }
#pragma unroll
        for (int nt = 0; nt < 4; nt++) {
            int t = 4 * w + nt;
            size_t off = ((size_t)(c * 16 + t) * 64 + L) * 8;
            short8 bh = *(const short8*)(a1h + off);
            short8 bl = *(const short8*)(a1l + off);
#pragma unroll
            for (int mt = 0; mt < 4; mt++) {
                acc2[nt][mt] = __builtin_amdgcn_mfma_f32_16x16x32_bf16(ahf[mt], bh, acc2[nt][mt], 0, 0, 0);
                acc2[nt][mt] = __builtin_amdgcn_mfma_f32_16x16x32_bf16(ahf[mt], bl, acc2[nt][mt], 0, 0, 0);
                acc2[nt][mt] = __builtin_amdgcn_mfma_f32_16x16x32_bf16(alf[mt], bh, acc2[nt][mt], 0, 0, 0);
            }
        }
    }

    // --- store P (C layout)
#pragma unroll
    for (int nt = 0; nt < 4; nt++) {
        int col = (4 * w + nt) * 16 + ln;
#pragma unroll
        for (int mt = 0; mt < 4; mt++) {
#pragma unroll
            for (int r = 0; r < 4; r++) {
                int row = n0 + mt * 16 + quad * 4 + r;
                if (row < N) P[(size_t)row * HID + col] = acc2[nt][mt][r];
            }
        }
    }
}

// ---------- logits epilogue
__global__ void k_logits(const float* __restrict__ P, const float* __restrict__ gbias,
                         const float* __restrict__ aw2, const float* __restrict__ ab2,
                         float* __restrict__ out, int N) {
    int lane = threadIdx.x & 63;
    int wv = threadIdx.x >> 6;
    int n = blockIdx.x * 4 + wv;
    if (n >= N) return;
    float4 p = *(const float4*)(P + (size_t)n * HID + 4 * lane);
    float4 gb = *(const float4*)(gbias + 4 * lane);
    float4 w2 = *(const float4*)(aw2 + 4 * lane);
    float v = fmaxf(p.x + gb.x, 0.f) * w2.x
            + fmaxf(p.y + gb.y, 0.f) * w2.y
            + fmaxf(p.z + gb.z, 0.f) * w2.z
            + fmaxf(p.w + gb.w, 0.f) * w2.w;
#pragma unroll
    for (int off = 32; off > 0; off >>= 1) v += __shfl_down(v, off, 64);
    if (lane == 0) out[n] = v + ab2[0];
}

// ---------- merged head prep
__global__ void k_heads(const float* __restrict__ gsum,
                        const float* __restrict__ aw1, const float* __restrict__ ab1,
                        float* __restrict__ gbias,
                        const float* __restrict__ cw1, const float* __restrict__ cb1,
                        const float* __restrict__ cw2, const float* __restrict__ cb2,
                        const float* __restrict__ cw3, const float* __restrict__ cb3,
                        float* __restrict__ sv_out, float invN) {
    int t = threadIdx.x;  // 512
    if (blockIdx.x == 0) {
        if (t < HID) {
            float s = ab1[t];
            for (int j = 0; j < HID; j++) s += gsum[j] * invN * aw1[(HID + j) * HID + t];
            gbias[t] = s;
        }
        return;
    }
    __shared__ float p[2 * HID];
    __shared__ float c1[2 * HID];
    __shared__ float c2[HID];
    p[t] = gsum[t & (HID - 1)] * invN;
    __syncthreads();
    float s = cb1[t];
    for (int i = 0; i < 2 * HID; i++) s += p[i] * cw1[i * 2 * HID + t];
    c1[t] = fmaxf(s, 0.f);
    __syncthreads();
    if (t < HID) {
        float s2 = cb2[t];
        for (int i = 0; i < 2 * HID; i++) s2 += c1[i] * cw2[i * HID + t];
        c2[t] = fmaxf(s2, 0.f) * cw3[t];
    }
    __syncthreads();
    for (int st = HID / 2; st > 0; st >>= 1) {
        if (t < st) c2[t] += c2[t + st];
        __syncthreads();
    }
    if (t == 0) sv_out[0] = c2[0] + cb3[0];
}

extern "C" void kernel_launch(void* const* d_in, const int* in_sizes, int n_in,
                              void* d_out, int out_size, void* d_ws, size_t ws_size,
                              hipStream_t stream) {
    const float* nf      = (const float*)d_in[0];
    const int*   ei      = (const int*)d_in[1];
    const int*   eid     = (const int*)d_in[2];
    const int*   epos    = (const int*)d_in[3];
    const float* id_emb  = (const float*)d_in[4];
    const float* pos_emb = (const float*)d_in[5];
    const float* ew_w1   = (const float*)d_in[6];
    const float* ew_b1   = (const float*)d_in[7];
    const float* ew_w2   = (const float*)d_in[8];
    const float* ew_b2   = (const float*)d_in[9];
    const float* c1w     = (const float*)d_in[10];
    const float* c1b     = (const float*)d_in[11];
    const float* c2w     = (const float*)d_in[12];
    const float* c2b     = (const float*)d_in[13];
    const float* aw1     = (const float*)d_in[14];
    const float* ab1     = (const float*)d_in[15];
    const float* aw2     = (const float*)d_in[16];
    const float* ab2     = (const float*)d_in[17];
    const float* cw1     = (const float*)d_in[18];
    const float* cb1     = (const float*)d_in[19];
    const float* cw2     = (const float*)d_in[20];
    const float* cb2     = (const float*)d_in[21];
    const float* cw3     = (const float*)d_in[22];
    const float* cb3     = (const float*)d_in[23];

    int N = in_sizes[0] / 3;
    int E = in_sizes[2];
    int NB = (N + 255) / 256;
    float invN = 1.f / (float)N;

    char* ws = (char*)d_ws;
    float* deg      = (float*)ws;                         ws += (size_t)N * 4;
    int*   cnt      = (int*)ws;                           ws += (size_t)N * 4;
    float* gsum     = (float*)ws;                         ws += HID * 4;
    ushort* Ah      = (ushort*)ws;                        ws += (size_t)N * HID * 2;
    ushort* Al      = (ushort*)ws;                        ws += (size_t)N * HID * 2;
    float* P        = (float*)ws;                         ws += (size_t)N * HID * 4;
    float* ew       = (float*)ws;                         ws += (size_t)E * 4;
    int2*  csr      = (int2*)ws;                          ws += (size_t)E * 8;
    int*   row_ptr  = (int*)ws;                           ws += (size_t)(N + 1) * 4;
    int*   cursor   = (int*)ws;                           ws += (size_t)N * 4;
    int*   bsums    = (int*)ws;                           ws += 256 * 4;
    float4* T3      = (float4*)ws;                        ws += (size_t)N * 16;
    float4* nf4     = (float4*)ws;                        ws += (size_t)N * 16;
    float* gbias    = (float*)ws;                         ws += HID * 4;
    ushort* w2h     = (ushort*)ws;                        ws += 65536 * 2;
    ushort* w2l     = (ushort*)ws;                        ws += 65536 * 2;
    ushort* a1h     = (ushort*)ws;                        ws += 65536 * 2;
    ushort* a1l     = (ushort*)ws;                        ws += 65536 * 2;

    float* out = (float*)d_out;  // [N] logits + [1] state value

    // --- zero deg+cnt in one memset (gsum zeroed in k_scan_a)
    hipMemsetAsync(deg, 0, (size_t)(2 * N) * sizeof(float), stream);

    // --- edge MLP + degree + histogram
    k_edge<<<(E + 255) / 256, 256, 0, stream>>>(eid, epos, id_emb, pos_emb,
                                                ew_w1, ew_b1, ew_w2, ew_b2, ei, ew, deg, cnt, E);

    // --- scan a (+ dinv + nf4 pack + gsum zero + wprep), then c (absorbs b)
    k_scan_a<<<NB, 256, 0, stream>>>(cnt, row_ptr, bsums, deg, nf, nf4, gsum,
                                     c2w, aw1, w2h, w2l, a1h, a1l, N);
    k_scan_c<<<NB, 256, 0, stream>>>(row_ptr, cursor, bsums, N, NB);

    // --- fill CSR
    k_fill<<<(E + 255) / 256, 256, 0, stream>>>(ei, ew, deg, cursor, csr, E);

    // --- layer 1 aggregate on raw features
    k_agg3<<<(N + 255) / 256, 256, 0, stream>>>(row_ptr, csr, nf4, deg, T3, N);

    // --- layer 2 aggregate; writes A as bf16 hi/lo
    k_gatherfused<<<(N + 3) / 4, 256, 0, stream>>>(row_ptr, csr, T3, deg, c1w, c1b, Ah, Al, N);

    // --- MFMA fused conv2-GEMM + actor-GEMM (+ colsum); 64-row tiles
    k_gemm_mfma<<<(N + 63) / 64, 256, 0, stream>>>(Ah, Al, c2b, w2h, w2l, a1h, a1l, P, gsum, N);

    // --- heads prep: gbias + critic value
    k_heads<<<2, 2 * HID, 0, stream>>>(gsum, aw1, ab1, gbias,
                                       cw1, cb1, cw2, cb2, cw3, cb3, out + N, invN);

    // --- logits epilogue
    k_logits<<<(N + 3) / 4, 256, 0, stream>>>(P, gbias, aw2, ab2, out, N);
}